// Round 3
// baseline (89781.683 us; speedup 1.0000x reference)
//
#include <hip/hip_runtime.h>

#define EMB   300
#define EMB2  600
#define NLAYERS 5
#define NN    100000
#define NE    400000
#define NG    1024
#define BN_EPS 1e-5f
#define MPAD  100096            // 782*128
#define NB_SC 391               // ceil(NN/256)

typedef __bf16 bf16;
typedef __attribute__((ext_vector_type(8))) __bf16 bf16x8;
typedef __attribute__((ext_vector_type(4))) float f32x4;

// ---------------- CSR build ----------------
__global__ void k_count(const int* __restrict__ dst, int* __restrict__ cnt) {
  int e = blockIdx.x * 256 + threadIdx.x;
  if (e < NE) atomicAdd(&cnt[dst[e]], 1);
}

__global__ void k_bsum(const int* __restrict__ cnt, int* __restrict__ bsum) {
  __shared__ int red[256];
  int i = blockIdx.x * 256 + threadIdx.x;
  red[threadIdx.x] = (i < NN) ? cnt[i] : 0;
  __syncthreads();
  for (int off = 128; off; off >>= 1) {
    if (threadIdx.x < off) red[threadIdx.x] += red[threadIdx.x + off];
    __syncthreads();
  }
  if (!threadIdx.x) bsum[blockIdx.x] = red[0];
}

__global__ void k_bscan(const int* __restrict__ bsum, int* __restrict__ bpre) {
  __shared__ int s[512];
  int t = threadIdx.x;
  s[t] = (t < NB_SC) ? bsum[t] : 0;
  __syncthreads();
  for (int off = 1; off < 512; off <<= 1) {
    int v = (t >= off) ? s[t - off] : 0;
    __syncthreads();
    s[t] += v;
    __syncthreads();
  }
  if (t < NB_SC) bpre[t] = t ? s[t - 1] : 0;
}

__global__ void k_expand(const int* __restrict__ cnt, const int* __restrict__ bpre,
                         int* __restrict__ rowptr, int* __restrict__ cursor) {
  __shared__ int s[256];
  int t = threadIdx.x, i = blockIdx.x * 256 + t;
  int v = (i < NN) ? cnt[i] : 0;
  s[t] = v;
  __syncthreads();
  for (int off = 1; off < 256; off <<= 1) {
    int u = (t >= off) ? s[t - off] : 0;
    __syncthreads();
    s[t] += u;
    __syncthreads();
  }
  int excl = bpre[blockIdx.x] + s[t] - v;
  if (i < NN) { rowptr[i] = excl; cursor[i] = excl; }
  if (i == NN - 1) rowptr[NN] = excl + v;
}

__global__ void k_fill(const int* __restrict__ ei, const int* __restrict__ ea,
                       int* __restrict__ cursor, int* __restrict__ packed) {
  int e = blockIdx.x * 256 + threadIdx.x;
  if (e >= NE) return;
  int d = ei[NE + e];
  int s = ei[e];
  int comb = ea[2 * e] * 3 + ea[2 * e + 1];
  int pos = atomicAdd(&cursor[d], 1);
  packed[pos] = s | (comb << 20);
}

// ---------------- init h ----------------
__global__ void k_init(const int* __restrict__ x, const float4* __restrict__ ae1,
                       const float4* __restrict__ ae2, float4* __restrict__ h) {
  int idx = blockIdx.x * 256 + threadIdx.x;
  if (idx >= NN * 75) return;
  int n = idx / 75, v = idx - n * 75;
  int x0 = x[2 * n], x1 = x[2 * n + 1];
  float4 a = ae1[x0 * 75 + v], b = ae2[x1 * 75 + v];
  float4 r; r.x = a.x + b.x; r.y = a.y + b.y; r.z = a.z + b.z; r.w = a.w + b.w;
  h[idx] = r;
}

// ---------------- weight/bias prep (split bf16, tripled-K layout, N-major) ----------
// B1n: [L][640][960]  rows n; k' in [0,320)=Wh, [320,640)=Wh, [640,960)=Wl
__global__ void k_prepw1(const float* __restrict__ W1, bf16* __restrict__ B1n) {
  int idx = blockIdx.x * 256 + threadIdx.x;
  if (idx >= 5 * 640 * 960) return;
  int l = idx / (640 * 960), rem = idx - l * (640 * 960);
  int n = rem / 960, kp = rem - n * 960;
  int reg = kp / 320, kk = kp - reg * 320;
  float w = (n < 600 && kk < 300) ? W1[(size_t)l * 300 * 600 + kk * 600 + n] : 0.f;
  bf16 hi = (bf16)w;
  B1n[idx] = (reg < 2) ? hi : (bf16)(w - (float)hi);
}

// B2n: [L][320][1920]  k' in [0,640)=Wh, [640,1280)=Wh, [1280,1920)=Wl
__global__ void k_prepw2(const float* __restrict__ W2, bf16* __restrict__ B2n) {
  int idx = blockIdx.x * 256 + threadIdx.x;
  if (idx >= 5 * 320 * 1920) return;
  int l = idx / (320 * 1920), rem = idx - l * (320 * 1920);
  int n = rem / 1920, kp = rem - n * 1920;
  int reg = kp / 640, kk = kp - reg * 640;
  float w = (n < 300 && kk < 600) ? W2[(size_t)l * 600 * 300 + kk * 300 + n] : 0.f;
  bf16 hi = (bf16)w;
  B2n[idx] = (reg < 2) ? hi : (bf16)(w - (float)hi);
}

__global__ void k_prepb(const float* __restrict__ b1, const float* __restrict__ b2,
                        float* __restrict__ b1p, float* __restrict__ b2p) {
  int idx = blockIdx.x * 256 + threadIdx.x;
  if (idx < 5 * 640) {
    int l = idx / 640, n = idx - l * 640;
    b1p[idx] = (n < 600) ? b1[l * 600 + n] : 0.f;
  } else if (idx < 5 * 640 + 5 * 320) {
    int j = idx - 5 * 640;
    int l = j / 320, n = j - l * 320;
    b2p[j] = (n < 300) ? b2[l * 300 + n] : 0.f;
  }
}

// ---------------- aggregation (wave per node) -> split bf16 A-buffer -------------
// aggS row layout (plain, 640 cols): [0,320)=hi (300 vals + 20 zeros), [320,640)=lo
__global__ __launch_bounds__(256) void k_agg(
    const float* __restrict__ h, const int* __restrict__ rowptr,
    const int* __restrict__ packed, const float* __restrict__ be1,
    const float* __restrict__ be2, bf16* __restrict__ aggS) {
  __shared__ float tab[9 * EMB];
  for (int i = threadIdx.x; i < 9 * EMB; i += 256) {
    int cc = i / EMB, d = i - cc * EMB;
    tab[i] = be1[(cc / 3) * EMB + d] + be2[(cc - (cc / 3) * 3) * EMB + d];
  }
  __syncthreads();
  int ty = threadIdx.x >> 6, lane = threadIdx.x & 63;
  int n = blockIdx.x * 4 + ty;
  float acc[5];
#pragma unroll
  for (int j = 0; j < 5; j++) {
    int d = lane + 64 * j;
    if (d < EMB) acc[j] = h[(size_t)n * EMB + d] + be1[4 * EMB + d] + be2[d];
  }
  int e0 = rowptr[n], e1 = rowptr[n + 1];
  for (int e = e0; e < e1; ++e) {
    int pk = packed[e];
    const float* hr = &h[(size_t)(pk & 0xFFFFF) * EMB];
    const float* tr = &tab[(pk >> 20) * EMB];
#pragma unroll
    for (int j = 0; j < 5; j++) {
      int d = lane + 64 * j;
      if (d < EMB) acc[j] += hr[d] + tr[d];
    }
  }
  bf16* row = aggS + (size_t)n * 640;
#pragma unroll
  for (int j = 0; j < 5; j++) {
    int d = lane + 64 * j;
    if (d < EMB) {
      float v = acc[j];
      bf16 hi = (bf16)v;
      row[d] = hi;
      row[320 + d] = (bf16)(v - (float)hi);
    } else if (d < 320) {
      row[d] = (bf16)0.f;
      row[320 + d] = (bf16)0.f;
    }
  }
}

// ---------------- MFMA GEMM (bf16x3 split, tripled K) ----------------
// A: row-major [*, lda] bf16; A k-tile source col = k0, or k0-DUPAT in dup region
// (A's 3rd K-section re-reads the hi part). B is fully materialized over the
// tripled K: ALWAYS indexed by k0 (round-2 bug: B used the A-remap).
// Bn: N-major [*, ldb] bf16. Tile 128x64, BK=64, 4 waves (2x2), 16x16x32 MFMA.
// MODE 1: out = Cs (h1 split, ld 1280): relu, hi at col, lo at col+640.
// MODE 2: out = Cf fp32 ld 300, write if col<300 && row<row_limit.
template <int KTILES, int DUPAT, int MODE>
__global__ __launch_bounds__(256) void k_mfma(
    const bf16* __restrict__ A, int lda,
    const bf16* __restrict__ Bn, int ldb,
    const float* __restrict__ bias,
    float* __restrict__ Cf, bf16* __restrict__ Cs, int row_limit) {
  __shared__ __align__(16) bf16 As[2][128 * 64];
  __shared__ __align__(16) bf16 Bs[2][64 * 64];
  const int t = threadIdx.x, lane = t & 63, wid = t >> 6;
  const int wr = wid >> 1, wc = wid & 1;
  const int row0 = blockIdx.y * 128, n0 = blockIdx.x * 64;

  uint4 ra[4], rb[2];
  auto gload = [&](int kt) {
    int k0 = kt * 64;
    int ksA = (k0 >= DUPAT) ? k0 - DUPAT : k0;   // A-only remap
#pragma unroll
    for (int i = 0; i < 4; i++) {
      int idx = t + i * 256, r = idx >> 3, s = idx & 7;
      ra[i] = *(const uint4*)(A + (size_t)(row0 + r) * lda + ksA + s * 8);
    }
#pragma unroll
    for (int i = 0; i < 2; i++) {
      int idx = t + i * 256, n = idx >> 3, s = idx & 7;
      rb[i] = *(const uint4*)(Bn + (size_t)(n0 + n) * ldb + k0 + s * 8);
    }
  };
  auto swr = [&](int buf) {
#pragma unroll
    for (int i = 0; i < 4; i++) {
      int idx = t + i * 256, r = idx >> 3, s = idx & 7;
      *(uint4*)((char*)&As[buf][0] + r * 128 + ((s ^ (r & 7)) << 4)) = ra[i];
    }
#pragma unroll
    for (int i = 0; i < 2; i++) {
      int idx = t + i * 256, n = idx >> 3, s = idx & 7;
      *(uint4*)((char*)&Bs[buf][0] + n * 128 + ((s ^ (n & 7)) << 4)) = rb[i];
    }
  };

  f32x4 acc[4][2] = {};
  gload(0);
  swr(0);
  int cur = 0;
#pragma unroll 2
  for (int kt = 0; kt < KTILES; kt++) {
    __syncthreads();
    if (kt + 1 < KTILES) gload(kt + 1);
#pragma unroll
    for (int kk = 0; kk < 2; kk++) {
      bf16x8 af[4], bfr[2];
#pragma unroll
      for (int mf = 0; mf < 4; mf++) {
        int r = wr * 64 + mf * 16 + (lane & 15);
        int c = (kk * 4 + (lane >> 4)) ^ (r & 7);
        af[mf] = *(const bf16x8*)((const char*)&As[cur][0] + r * 128 + (c << 4));
      }
#pragma unroll
      for (int nf = 0; nf < 2; nf++) {
        int n = wc * 32 + nf * 16 + (lane & 15);
        int c = (kk * 4 + (lane >> 4)) ^ (n & 7);
        bfr[nf] = *(const bf16x8*)((const char*)&Bs[cur][0] + n * 128 + (c << 4));
      }
#pragma unroll
      for (int mf = 0; mf < 4; mf++)
#pragma unroll
        for (int nf = 0; nf < 2; nf++)
          acc[mf][nf] = __builtin_amdgcn_mfma_f32_16x16x32_bf16(
              af[mf], bfr[nf], acc[mf][nf], 0, 0, 0);
    }
    if (kt + 1 < KTILES) swr(cur ^ 1);
    cur ^= 1;
  }

  const int rq = (lane >> 4) << 2;   // 0,4,8,12
  const int cl = lane & 15;
#pragma unroll
  for (int mf = 0; mf < 4; mf++)
#pragma unroll
    for (int nf = 0; nf < 2; nf++)
#pragma unroll
      for (int r = 0; r < 4; r++) {
        int grow = row0 + wr * 64 + mf * 16 + rq + r;
        int gcol = n0 + wc * 32 + nf * 16 + cl;
        float v = acc[mf][nf][r] + bias[gcol];
        if (MODE == 1) {
          v = fmaxf(v, 0.f);
          bf16 hi = (bf16)v;
          Cs[(size_t)grow * 1280 + gcol] = hi;
          Cs[(size_t)grow * 1280 + 640 + gcol] = (bf16)(v - (float)hi);
        } else {
          if (grow < row_limit && gcol < 300) Cf[(size_t)grow * 300 + gcol] = v;
        }
      }
}

// ---------------- batchnorm ----------------
__global__ void k_bnstats(const float* __restrict__ h, float* __restrict__ stats) {
  int b = blockIdx.x, t = threadIdx.x;
  int r0 = b * 196, r1 = r0 + 196; if (r1 > NN) r1 = NN;
  if (r0 >= NN) return;
  int c2 = t + 256;
  float s1 = 0, ss1 = 0, s2 = 0, ss2 = 0;
  for (int r = r0; r < r1; ++r) {
    float v1 = h[(size_t)r * EMB + t];
    s1 += v1; ss1 += v1 * v1;
    if (c2 < EMB) { float v2 = h[(size_t)r * EMB + c2]; s2 += v2; ss2 += v2 * v2; }
  }
  atomicAdd(&stats[t], s1); atomicAdd(&stats[EMB + t], ss1);
  if (c2 < EMB) { atomicAdd(&stats[c2], s2); atomicAdd(&stats[EMB + c2], ss2); }
}

__global__ void k_bnfinal(const float* __restrict__ stats, const float* __restrict__ sc,
                          const float* __restrict__ bi, float* __restrict__ coef) {
  int c = threadIdx.x;
  if (c >= EMB) return;
  float mean = stats[c] * (1.0f / NN);
  float var  = stats[EMB + c] * (1.0f / NN) - mean * mean;
  float inv  = rsqrtf(var + BN_EPS);
  float a = inv * sc[c];
  coef[c] = a;
  coef[EMB + c] = bi[c] - mean * a;
}

__global__ void k_bnapply(float4* __restrict__ h, const float* __restrict__ coef, int relu) {
  int idx = blockIdx.x * 256 + threadIdx.x;
  if (idx >= NN * 75) return;
  int v = idx % 75;
  float4 a  = *(const float4*)&coef[v * 4];
  float4 bb = *(const float4*)&coef[EMB + v * 4];
  float4 x = h[idx];
  x.x = x.x * a.x + bb.x; x.y = x.y * a.y + bb.y;
  x.z = x.z * a.z + bb.z; x.w = x.w * a.w + bb.w;
  if (relu) { x.x = fmaxf(x.x, 0.f); x.y = fmaxf(x.y, 0.f);
              x.z = fmaxf(x.z, 0.f); x.w = fmaxf(x.w, 0.f); }
  h[idx] = x;
}

// ---------------- pooling ----------------
__device__ __forceinline__ int lowerb(const int* a, int n, int v) {
  int lo = 0, hi = n;
  while (lo < hi) { int mid = (lo + hi) >> 1; if (a[mid] < v) lo = mid + 1; else hi = mid; }
  return lo;
}

__global__ void k_pool(const float* __restrict__ h, const int* __restrict__ batch,
                       float* __restrict__ pooled) {
  int g = blockIdx.x;
  __shared__ int se[2];
  if (threadIdx.x == 0) { se[0] = lowerb(batch, NN, g); se[1] = lowerb(batch, NN, g + 1); }
  __syncthreads();
  int start = se[0], end = se[1];
  float cntf = (float)((end - start) > 1 ? (end - start) : 1);
  for (int c = threadIdx.x; c < EMB; c += 256) {
    float s = 0.f;
    for (int r = start; r < end; ++r) s += h[(size_t)r * EMB + c];
    pooled[(size_t)g * EMB + c] = s / cntf;
  }
}

// ---------------- projection head ----------------
template <bool RELU>
__global__ void k_rowgemm(const float* __restrict__ X, const float* __restrict__ W,
                          const float* __restrict__ bias, float* __restrict__ Y) {
  int g = blockIdx.x;
  __shared__ float row[EMB];
  for (int i = threadIdx.x; i < EMB; i += 256) row[i] = X[(size_t)g * EMB + i];
  __syncthreads();
  for (int c = threadIdx.x; c < EMB; c += 256) {
    float acc = bias[c];
    for (int k = 0; k < EMB; k++) acc += row[k] * W[(size_t)k * EMB + c];
    if (RELU) acc = fmaxf(acc, 0.f);
    Y[(size_t)g * EMB + c] = acc;
  }
}

__global__ void k_norm(float* __restrict__ p) {
  int g = blockIdx.x;
  __shared__ float red[256];
  float s = 0.f;
  for (int c = threadIdx.x; c < EMB; c += 256) { float v = p[(size_t)g * EMB + c]; s += v * v; }
  red[threadIdx.x] = s; __syncthreads();
  for (int off = 128; off > 0; off >>= 1) {
    if (threadIdx.x < off) red[threadIdx.x] += red[threadIdx.x + off];
    __syncthreads();
  }
  float inv = 1.0f / fmaxf(sqrtf(red[0]), 1e-12f);
  for (int c = threadIdx.x; c < EMB; c += 256) p[(size_t)g * EMB + c] *= inv;
}

__global__ __launch_bounds__(256) void k_logits(const float* __restrict__ feats,
                                                float* __restrict__ out) {
  __shared__ float SA[16 * EMB];
  __shared__ float SB[16 * EMB];
  int t = threadIdx.y * 16 + threadIdx.x;
  int i0 = blockIdx.y * 16, j0 = blockIdx.x * 16;
  for (int idx = t; idx < 16 * EMB; idx += 256) {
    int r = idx / EMB, c = idx - r * EMB;
    SA[idx] = feats[(size_t)(i0 + r) * EMB + c];
    SB[idx] = feats[(size_t)(512 + j0 + r) * EMB + c];
  }
  __syncthreads();
  float acc = 0.f;
  const float* a = &SA[threadIdx.y * EMB];
  const float* b = &SB[threadIdx.x * EMB];
  for (int k = 0; k < EMB; k++) acc += a[k] * b[k];
  out[(size_t)(i0 + threadIdx.y) * 512 + j0 + threadIdx.x] = acc / 0.04f;
}

// ---------------- host ----------------
extern "C" void kernel_launch(void* const* d_in, const int* in_sizes, int n_in,
                              void* d_out, int out_size, void* d_ws, size_t ws_size,
                              hipStream_t stream) {
  const int*   x         = (const int*)d_in[0];
  const int*   ei        = (const int*)d_in[1];
  const int*   ea        = (const int*)d_in[2];
  const int*   batch     = (const int*)d_in[3];
  const float* atom_emb1 = (const float*)d_in[4];
  const float* atom_emb2 = (const float*)d_in[5];
  const float* bond_emb1 = (const float*)d_in[6];
  const float* bond_emb2 = (const float*)d_in[7];
  const float* W1        = (const float*)d_in[8];
  const float* b1        = (const float*)d_in[9];
  const float* W2        = (const float*)d_in[10];
  const float* b2        = (const float*)d_in[11];
  const float* bn_scale  = (const float*)d_in[12];
  const float* bn_bias   = (const float*)d_in[13];
  const float* pW1       = (const float*)d_in[14];
  const float* pb1       = (const float*)d_in[15];
  const float* pW2       = (const float*)d_in[16];
  const float* pb2       = (const float*)d_in[17];
  float* out = (float*)d_out;

  char* w = (char*)d_ws;
  size_t used = 0;
  auto alloc = [&](size_t bytes) {
    char* p = w + used;
    used += (bytes + 255) & ~(size_t)255;
    return p;
  };
  float* h      = (float*)alloc((size_t)NN * EMB * 4);
  bf16*  aggS   = (bf16*)alloc((size_t)MPAD * 640 * 2);
  bf16*  B1n    = (bf16*)alloc((size_t)5 * 640 * 960 * 2);
  bf16*  B2n    = (bf16*)alloc((size_t)5 * 320 * 1920 * 2);
  float* b1p    = (float*)alloc(5 * 640 * 4);
  float* b2p    = (float*)alloc(5 * 320 * 4);
  int*   cnt    = (int*)alloc(NN * 4);
  int*   rowptr = (int*)alloc((NN + 4) * 4);
  int*   cursor = (int*)alloc(NN * 4);
  int*   packed = (int*)alloc(NE * 4);
  int*   bsum   = (int*)alloc(NB_SC * 4);
  int*   bpre   = (int*)alloc(NB_SC * 4);
  float* stats  = (float*)alloc(EMB2 * 4);
  float* coef   = (float*)alloc(EMB2 * 4);
  float* pooled = (float*)alloc((size_t)NG * EMB * 4);
  float* t1     = (float*)alloc((size_t)NG * EMB * 4);
  float* feats  = (float*)alloc((size_t)NG * EMB * 4);
  // h1 split chunk buffer: [CHUNK][1280] bf16
  long long avail = (long long)ws_size - (long long)used;
  long long rows = avail / (1280 * 2);
  int CHUNK = (int)(rows < 25088 ? rows : 25088);
  CHUNK &= ~127;
  if (CHUNK < 128) CHUNK = 128;
  bf16* h1S = (bf16*)(w + used);

  // CSR build
  hipMemsetAsync(cnt, 0, NN * 4, stream);
  k_count<<<(NE + 255) / 256, 256, 0, stream>>>(ei + NE, cnt);
  k_bsum<<<NB_SC, 256, 0, stream>>>(cnt, bsum);
  k_bscan<<<1, 512, 0, stream>>>(bsum, bpre);
  k_expand<<<NB_SC, 256, 0, stream>>>(cnt, bpre, rowptr, cursor);
  k_fill<<<(NE + 255) / 256, 256, 0, stream>>>(ei, ea, cursor, packed);

  // zero aggS padding rows [NN, MPAD) once (read as A rows of the last tile;
  // output discarded via row_limit, but keep them finite)
  hipMemsetAsync(aggS + (size_t)NN * 640, 0, (size_t)(MPAD - NN) * 640 * 2, stream);

  // weights prep
  k_prepw1<<<(5 * 640 * 960 + 255) / 256, 256, 0, stream>>>(W1, B1n);
  k_prepw2<<<(5 * 320 * 1920 + 255) / 256, 256, 0, stream>>>(W2, B2n);
  k_prepb<<<(5 * 640 + 5 * 320 + 255) / 256, 256, 0, stream>>>(b1, b2, b1p, b2p);

  // h0
  k_init<<<(NN * 75 + 255) / 256, 256, 0, stream>>>(
      x, (const float4*)atom_emb1, (const float4*)atom_emb2, (float4*)h);

  for (int l = 0; l < NLAYERS; ++l) {
    const float* be1 = bond_emb1 + (size_t)l * 6 * EMB;
    const float* be2 = bond_emb2 + (size_t)l * 3 * EMB;
    k_agg<<<NN / 4, 256, 0, stream>>>(h, rowptr, packed, be1, be2, aggS);

    for (int c0 = 0; c0 < NN; c0 += CHUNK) {
      int m = NN - c0 < CHUNK ? NN - c0 : CHUNK;
      int mt = (m + 127) / 128;
      k_mfma<15, 640, 1><<<dim3(10, mt), 256, 0, stream>>>(
          aggS + (size_t)c0 * 640, 640, B1n + (size_t)l * 640 * 960, 960,
          b1p + l * 640, nullptr, h1S, 0);
      k_mfma<30, 1280, 2><<<dim3(5, mt), 256, 0, stream>>>(
          h1S, 1280, B2n + (size_t)l * 320 * 1920, 1920,
          b2p + l * 320, h + (size_t)c0 * 300, nullptr, NN - c0);
    }

    hipMemsetAsync(stats, 0, EMB2 * 4, stream);
    k_bnstats<<<512, 256, 0, stream>>>(h, stats);
    k_bnfinal<<<1, 320, 0, stream>>>(stats, bn_scale + (size_t)l * EMB,
                                     bn_bias + (size_t)l * EMB, coef);
    k_bnapply<<<(NN * 75 + 255) / 256, 256, 0, stream>>>((float4*)h, coef, l < NLAYERS - 1);
  }

  k_pool<<<NG, 256, 0, stream>>>(h, batch, pooled);
  k_rowgemm<true><<<NG, 256, 0, stream>>>(pooled, pW1, pb1, t1);
  k_rowgemm<false><<<NG, 256, 0, stream>>>(t1, pW2, pb2, feats);
  k_norm<<<NG, 256, 0, stream>>>(feats);
  k_logits<<<dim3(32, 32), dim3(16, 16), 0, stream>>>(feats, out);
}

// Round 4
// 15948.396 us; speedup vs baseline: 5.6295x; 5.6295x over previous
//
#include <hip/hip_runtime.h>

#define EMB   300
#define EMB2  600
#define NLAYERS 5
#define NN    100000
#define NE    400000
#define NG    1024
#define BN_EPS 1e-5f
#define MPAD  100096            // 782*128
#define NB_SC 391               // ceil(NN/256)

// aggS: [MPAD][608] bf16: col [0,304)=hi (300 real + 4 zero), [304,608)=lo
// h1S : [CHUNK][1216] bf16: col [0,608)=hi (600 real + 8 zero), [608,1216)=lo
// B1n : [L][640 n][640 k]  bf16: k [0,320)=W1h (kk<300 real), [320,640)=W1l
// B2n : [L][320 n][1280 k] bf16: k [0,640)=W2h (kk<600 real), [640,1280)=W2l
// Tile-tail overreads of A (cols past the stored row) pair with ZERO B rows.

typedef __bf16 bf16;
typedef __attribute__((ext_vector_type(8))) __bf16 bf16x8;
typedef __attribute__((ext_vector_type(4))) float f32x4;

// ---------------- CSR build ----------------
__global__ void k_count(const int* __restrict__ dst, int* __restrict__ cnt) {
  int e = blockIdx.x * 256 + threadIdx.x;
  if (e < NE) atomicAdd(&cnt[dst[e]], 1);
}

__global__ void k_bsum(const int* __restrict__ cnt, int* __restrict__ bsum) {
  __shared__ int red[256];
  int i = blockIdx.x * 256 + threadIdx.x;
  red[threadIdx.x] = (i < NN) ? cnt[i] : 0;
  __syncthreads();
  for (int off = 128; off; off >>= 1) {
    if (threadIdx.x < off) red[threadIdx.x] += red[threadIdx.x + off];
    __syncthreads();
  }
  if (!threadIdx.x) bsum[blockIdx.x] = red[0];
}

__global__ void k_bscan(const int* __restrict__ bsum, int* __restrict__ bpre) {
  __shared__ int s[512];
  int t = threadIdx.x;
  s[t] = (t < NB_SC) ? bsum[t] : 0;
  __syncthreads();
  for (int off = 1; off < 512; off <<= 1) {
    int v = (t >= off) ? s[t - off] : 0;
    __syncthreads();
    s[t] += v;
    __syncthreads();
  }
  if (t < NB_SC) bpre[t] = t ? s[t - 1] : 0;
}

__global__ void k_expand(const int* __restrict__ cnt, const int* __restrict__ bpre,
                         int* __restrict__ rowptr, int* __restrict__ cursor) {
  __shared__ int s[256];
  int t = threadIdx.x, i = blockIdx.x * 256 + t;
  int v = (i < NN) ? cnt[i] : 0;
  s[t] = v;
  __syncthreads();
  for (int off = 1; off < 256; off <<= 1) {
    int u = (t >= off) ? s[t - off] : 0;
    __syncthreads();
    s[t] += u;
    __syncthreads();
  }
  int excl = bpre[blockIdx.x] + s[t] - v;
  if (i < NN) { rowptr[i] = excl; cursor[i] = excl; }
  if (i == NN - 1) rowptr[NN] = excl + v;
}

__global__ void k_fill(const int* __restrict__ ei, const int* __restrict__ ea,
                       int* __restrict__ cursor, int* __restrict__ packed) {
  int e = blockIdx.x * 256 + threadIdx.x;
  if (e >= NE) return;
  int d = ei[NE + e];
  int s = ei[e];
  int comb = ea[2 * e] * 3 + ea[2 * e + 1];
  int pos = atomicAdd(&cursor[d], 1);
  packed[pos] = s | (comb << 20);
}

// ---------------- init h ----------------
__global__ void k_init(const int* __restrict__ x, const float4* __restrict__ ae1,
                       const float4* __restrict__ ae2, float4* __restrict__ h) {
  int idx = blockIdx.x * 256 + threadIdx.x;
  if (idx >= NN * 75) return;
  int n = idx / 75, v = idx - n * 75;
  int x0 = x[2 * n], x1 = x[2 * n + 1];
  float4 a = ae1[x0 * 75 + v], b = ae2[x1 * 75 + v];
  float4 r; r.x = a.x + b.x; r.y = a.y + b.y; r.z = a.z + b.z; r.w = a.w + b.w;
  h[idx] = r;
}

// ---------------- weight/bias prep (split bf16, dup-free, N-major) ----------
__global__ void k_prepw1(const float* __restrict__ W1, bf16* __restrict__ B1n) {
  int idx = blockIdx.x * 256 + threadIdx.x;
  if (idx >= 5 * 640 * 640) return;
  int l = idx / (640 * 640), rem = idx - l * (640 * 640);
  int n = rem / 640, kp = rem - n * 640;
  int lo = kp >= 320;
  int kk = lo ? kp - 320 : kp;
  float w = (n < 600 && kk < 300) ? W1[(size_t)l * 300 * 600 + kk * 600 + n] : 0.f;
  bf16 hi = (bf16)w;
  B1n[idx] = lo ? (bf16)(w - (float)hi) : hi;
}

__global__ void k_prepw2(const float* __restrict__ W2, bf16* __restrict__ B2n) {
  int idx = blockIdx.x * 256 + threadIdx.x;
  if (idx >= 5 * 320 * 1280) return;
  int l = idx / (320 * 1280), rem = idx - l * (320 * 1280);
  int n = rem / 1280, kp = rem - n * 1280;
  int lo = kp >= 640;
  int kk = lo ? kp - 640 : kp;
  float w = (n < 300 && kk < 600) ? W2[(size_t)l * 600 * 300 + kk * 300 + n] : 0.f;
  bf16 hi = (bf16)w;
  B2n[idx] = lo ? (bf16)(w - (float)hi) : hi;
}

__global__ void k_prepb(const float* __restrict__ b1, const float* __restrict__ b2,
                        float* __restrict__ b1p, float* __restrict__ b2p) {
  int idx = blockIdx.x * 256 + threadIdx.x;
  if (idx < 5 * 640) {
    int l = idx / 640, n = idx - l * 640;
    b1p[idx] = (n < 600) ? b1[l * 600 + n] : 0.f;
  } else if (idx < 5 * 640 + 5 * 320) {
    int j = idx - 5 * 640;
    int l = j / 320, n = j - l * 320;
    b2p[j] = (n < 300) ? b2[l * 300 + n] : 0.f;
  }
}

// ---------------- aggregation (wave per node) -> split bf16 A-buffer -------------
__global__ __launch_bounds__(256) void k_agg(
    const float* __restrict__ h, const int* __restrict__ rowptr,
    const int* __restrict__ packed, const float* __restrict__ be1,
    const float* __restrict__ be2, bf16* __restrict__ aggS) {
  __shared__ float tab[9 * EMB];
  for (int i = threadIdx.x; i < 9 * EMB; i += 256) {
    int cc = i / EMB, d = i - cc * EMB;
    tab[i] = be1[(cc / 3) * EMB + d] + be2[(cc - (cc / 3) * 3) * EMB + d];
  }
  __syncthreads();
  int ty = threadIdx.x >> 6, lane = threadIdx.x & 63;
  int n = blockIdx.x * 4 + ty;
  float acc[5];
#pragma unroll
  for (int j = 0; j < 5; j++) {
    int d = lane + 64 * j;
    if (d < EMB) acc[j] = h[(size_t)n * EMB + d] + be1[4 * EMB + d] + be2[d];
  }
  int e0 = rowptr[n], e1 = rowptr[n + 1];
  for (int e = e0; e < e1; ++e) {
    int pk = packed[e];
    const float* hr = &h[(size_t)(pk & 0xFFFFF) * EMB];
    const float* tr = &tab[(pk >> 20) * EMB];
#pragma unroll
    for (int j = 0; j < 5; j++) {
      int d = lane + 64 * j;
      if (d < EMB) acc[j] += hr[d] + tr[d];
    }
  }
  bf16* row = aggS + (size_t)n * 608;
#pragma unroll
  for (int j = 0; j < 5; j++) {
    int d = lane + 64 * j;
    if (d < EMB) {
      float v = acc[j];
      bf16 hi = (bf16)v;
      row[d] = hi;
      row[304 + d] = (bf16)(v - (float)hi);
    } else if (d < 304) {
      row[d] = (bf16)0.f;
      row[304 + d] = (bf16)0.f;
    }
  }
}

// ---------------- MFMA GEMM (bf16x3 split, tripled K, dup-free B) ----------------
// Sections over kt: [0,KS)=Ah*Bh, [KS,2KS)=Al*Bh, [2KS,3KS)=Ah*Bl.
// A col: kbase (+A_LO if sect1).  B col: kbase (+B_LO if sect2).
// Tile 128x64, BK=64, 4 waves (2x2), 16x16x32 MFMA, double-buffered LDS,
// XOR-swizzled stores/reads.
// MODE 1: Cs = h1 split (ld 1216): relu, hi at col (<608), lo at col+608.
// MODE 2: Cf fp32 ld 300, write if col<300 && row<row_limit.
template <int K_SECT, int LDA, int LDB, int A_LO, int B_LO, int MODE>
__global__ __launch_bounds__(256) void k_mfma(
    const bf16* __restrict__ A,
    const bf16* __restrict__ Bn,
    const float* __restrict__ bias,
    float* __restrict__ Cf, bf16* __restrict__ Cs, int row_limit) {
  constexpr int KTILES = 3 * K_SECT;
  __shared__ __align__(16) bf16 As[2][128 * 64];
  __shared__ __align__(16) bf16 Bs[2][64 * 64];
  const int t = threadIdx.x, lane = t & 63, wid = t >> 6;
  const int wr = wid >> 1, wc = wid & 1;
  const int row0 = blockIdx.y * 128, n0 = blockIdx.x * 64;

  uint4 ra[4], rb[2];
  auto gload = [&](int kt) {
    int sect = (kt >= 2 * K_SECT) ? 2 : ((kt >= K_SECT) ? 1 : 0);
    int kbase = (kt - sect * K_SECT) * 64;
    int kA = kbase + (sect == 1 ? A_LO : 0);
    int kB = kbase + (sect == 2 ? B_LO : 0);
#pragma unroll
    for (int i = 0; i < 4; i++) {
      int idx = t + i * 256, r = idx >> 3, s = idx & 7;
      ra[i] = *(const uint4*)(A + (size_t)(row0 + r) * LDA + kA + s * 8);
    }
#pragma unroll
    for (int i = 0; i < 2; i++) {
      int idx = t + i * 256, n = idx >> 3, s = idx & 7;
      rb[i] = *(const uint4*)(Bn + (size_t)(n0 + n) * LDB + kB + s * 8);
    }
  };
  auto swr = [&](int buf) {
#pragma unroll
    for (int i = 0; i < 4; i++) {
      int idx = t + i * 256, r = idx >> 3, s = idx & 7;
      *(uint4*)((char*)&As[buf][0] + r * 128 + ((s ^ (r & 7)) << 4)) = ra[i];
    }
#pragma unroll
    for (int i = 0; i < 2; i++) {
      int idx = t + i * 256, n = idx >> 3, s = idx & 7;
      *(uint4*)((char*)&Bs[buf][0] + n * 128 + ((s ^ (n & 7)) << 4)) = rb[i];
    }
  };

  f32x4 acc[4][2] = {};
  gload(0);
  swr(0);
  int cur = 0;
#pragma unroll 2
  for (int kt = 0; kt < KTILES; kt++) {
    __syncthreads();
    if (kt + 1 < KTILES) gload(kt + 1);
#pragma unroll
    for (int kk = 0; kk < 2; kk++) {
      bf16x8 af[4], bfr[2];
#pragma unroll
      for (int mf = 0; mf < 4; mf++) {
        int r = wr * 64 + mf * 16 + (lane & 15);
        int c = (kk * 4 + (lane >> 4)) ^ (r & 7);
        af[mf] = *(const bf16x8*)((const char*)&As[cur][0] + r * 128 + (c << 4));
      }
#pragma unroll
      for (int nf = 0; nf < 2; nf++) {
        int n = wc * 32 + nf * 16 + (lane & 15);
        int c = (kk * 4 + (lane >> 4)) ^ (n & 7);
        bfr[nf] = *(const bf16x8*)((const char*)&Bs[cur][0] + n * 128 + (c << 4));
      }
#pragma unroll
      for (int mf = 0; mf < 4; mf++)
#pragma unroll
        for (int nf = 0; nf < 2; nf++)
          acc[mf][nf] = __builtin_amdgcn_mfma_f32_16x16x32_bf16(
              af[mf], bfr[nf], acc[mf][nf], 0, 0, 0);
    }
    if (kt + 1 < KTILES) swr(cur ^ 1);
    cur ^= 1;
  }

  const int rq = (lane >> 4) << 2;   // 0,4,8,12
  const int cl = lane & 15;
#pragma unroll
  for (int mf = 0; mf < 4; mf++)
#pragma unroll
    for (int nf = 0; nf < 2; nf++)
#pragma unroll
      for (int r = 0; r < 4; r++) {
        int grow = row0 + wr * 64 + mf * 16 + rq + r;
        int gcol = n0 + wc * 32 + nf * 16 + cl;
        float v = acc[mf][nf][r] + bias[gcol];
        if (MODE == 1) {
          if (gcol < 608) {
            v = fmaxf(v, 0.f);
            bf16 hi = (bf16)v;
            Cs[(size_t)grow * 1216 + gcol] = hi;
            Cs[(size_t)grow * 1216 + 608 + gcol] = (bf16)(v - (float)hi);
          }
        } else {
          if (grow < row_limit && gcol < 300) Cf[(size_t)grow * 300 + gcol] = v;
        }
      }
}

// ---------------- batchnorm ----------------
__global__ void k_bnstats(const float* __restrict__ h, float* __restrict__ stats) {
  int b = blockIdx.x, t = threadIdx.x;
  int r0 = b * 196, r1 = r0 + 196; if (r1 > NN) r1 = NN;
  if (r0 >= NN) return;
  int c2 = t + 256;
  float s1 = 0, ss1 = 0, s2 = 0, ss2 = 0;
  for (int r = r0; r < r1; ++r) {
    float v1 = h[(size_t)r * EMB + t];
    s1 += v1; ss1 += v1 * v1;
    if (c2 < EMB) { float v2 = h[(size_t)r * EMB + c2]; s2 += v2; ss2 += v2 * v2; }
  }
  atomicAdd(&stats[t], s1); atomicAdd(&stats[EMB + t], ss1);
  if (c2 < EMB) { atomicAdd(&stats[c2], s2); atomicAdd(&stats[EMB + c2], ss2); }
}

__global__ void k_bnfinal(const float* __restrict__ stats, const float* __restrict__ sc,
                          const float* __restrict__ bi, float* __restrict__ coef) {
  int c = threadIdx.x;
  if (c >= EMB) return;
  float mean = stats[c] * (1.0f / NN);
  float var  = stats[EMB + c] * (1.0f / NN) - mean * mean;
  float inv  = rsqrtf(var + BN_EPS);
  float a = inv * sc[c];
  coef[c] = a;
  coef[EMB + c] = bi[c] - mean * a;
}

__global__ void k_bnapply(float4* __restrict__ h, const float* __restrict__ coef, int relu) {
  int idx = blockIdx.x * 256 + threadIdx.x;
  if (idx >= NN * 75) return;
  int v = idx % 75;
  float4 a  = *(const float4*)&coef[v * 4];
  float4 bb = *(const float4*)&coef[EMB + v * 4];
  float4 x = h[idx];
  x.x = x.x * a.x + bb.x; x.y = x.y * a.y + bb.y;
  x.z = x.z * a.z + bb.z; x.w = x.w * a.w + bb.w;
  if (relu) { x.x = fmaxf(x.x, 0.f); x.y = fmaxf(x.y, 0.f);
              x.z = fmaxf(x.z, 0.f); x.w = fmaxf(x.w, 0.f); }
  h[idx] = x;
}

// ---------------- pooling ----------------
__device__ __forceinline__ int lowerb(const int* a, int n, int v) {
  int lo = 0, hi = n;
  while (lo < hi) { int mid = (lo + hi) >> 1; if (a[mid] < v) lo = mid + 1; else hi = mid; }
  return lo;
}

__global__ void k_pool(const float* __restrict__ h, const int* __restrict__ batch,
                       float* __restrict__ pooled) {
  int g = blockIdx.x;
  __shared__ int se[2];
  if (threadIdx.x == 0) { se[0] = lowerb(batch, NN, g); se[1] = lowerb(batch, NN, g + 1); }
  __syncthreads();
  int start = se[0], end = se[1];
  float cntf = (float)((end - start) > 1 ? (end - start) : 1);
  for (int c = threadIdx.x; c < EMB; c += 256) {
    float s = 0.f;
    for (int r = start; r < end; ++r) s += h[(size_t)r * EMB + c];
    pooled[(size_t)g * EMB + c] = s / cntf;
  }
}

// ---------------- projection head ----------------
template <bool RELU>
__global__ void k_rowgemm(const float* __restrict__ X, const float* __restrict__ W,
                          const float* __restrict__ bias, float* __restrict__ Y) {
  int g = blockIdx.x;
  __shared__ float row[EMB];
  for (int i = threadIdx.x; i < EMB; i += 256) row[i] = X[(size_t)g * EMB + i];
  __syncthreads();
  for (int c = threadIdx.x; c < EMB; c += 256) {
    float acc = bias[c];
    for (int k = 0; k < EMB; k++) acc += row[k] * W[(size_t)k * EMB + c];
    if (RELU) acc = fmaxf(acc, 0.f);
    Y[(size_t)g * EMB + c] = acc;
  }
}

__global__ void k_norm(float* __restrict__ p) {
  int g = blockIdx.x;
  __shared__ float red[256];
  float s = 0.f;
  for (int c = threadIdx.x; c < EMB; c += 256) { float v = p[(size_t)g * EMB + c]; s += v * v; }
  red[threadIdx.x] = s; __syncthreads();
  for (int off = 128; off > 0; off >>= 1) {
    if (threadIdx.x < off) red[threadIdx.x] += red[threadIdx.x + off];
    __syncthreads();
  }
  float inv = 1.0f / fmaxf(sqrtf(red[0]), 1e-12f);
  for (int c = threadIdx.x; c < EMB; c += 256) p[(size_t)g * EMB + c] *= inv;
}

__global__ __launch_bounds__(256) void k_logits(const float* __restrict__ feats,
                                                float* __restrict__ out) {
  __shared__ float SA[16 * EMB];
  __shared__ float SB[16 * EMB];
  int t = threadIdx.y * 16 + threadIdx.x;
  int i0 = blockIdx.y * 16, j0 = blockIdx.x * 16;
  for (int idx = t; idx < 16 * EMB; idx += 256) {
    int r = idx / EMB, c = idx - r * EMB;
    SA[idx] = feats[(size_t)(i0 + r) * EMB + c];
    SB[idx] = feats[(size_t)(512 + j0 + r) * EMB + c];
  }
  __syncthreads();
  float acc = 0.f;
  const float* a = &SA[threadIdx.y * EMB];
  const float* b = &SB[threadIdx.x * EMB];
  for (int k = 0; k < EMB; k++) acc += a[k] * b[k];
  out[(size_t)(i0 + threadIdx.y) * 512 + j0 + threadIdx.x] = acc / 0.04f;
}

// ---------------- host ----------------
extern "C" void kernel_launch(void* const* d_in, const int* in_sizes, int n_in,
                              void* d_out, int out_size, void* d_ws, size_t ws_size,
                              hipStream_t stream) {
  const int*   x         = (const int*)d_in[0];
  const int*   ei        = (const int*)d_in[1];
  const int*   ea        = (const int*)d_in[2];
  const int*   batch     = (const int*)d_in[3];
  const float* atom_emb1 = (const float*)d_in[4];
  const float* atom_emb2 = (const float*)d_in[5];
  const float* bond_emb1 = (const float*)d_in[6];
  const float* bond_emb2 = (const float*)d_in[7];
  const float* W1        = (const float*)d_in[8];
  const float* b1        = (const float*)d_in[9];
  const float* W2        = (const float*)d_in[10];
  const float* b2        = (const float*)d_in[11];
  const float* bn_scale  = (const float*)d_in[12];
  const float* bn_bias   = (const float*)d_in[13];
  const float* pW1       = (const float*)d_in[14];
  const float* pb1       = (const float*)d_in[15];
  const float* pW2       = (const float*)d_in[16];
  const float* pb2       = (const float*)d_in[17];
  float* out = (float*)d_out;

  char* w = (char*)d_ws;
  size_t used = 0;
  auto alloc = [&](size_t bytes) {
    char* p = w + used;
    used += (bytes + 255) & ~(size_t)255;
    return p;
  };
  float* h      = (float*)alloc((size_t)NN * EMB * 4);           // 120.0 MB
  bf16*  aggS   = (bf16*)alloc((size_t)MPAD * 608 * 2);          // 121.7 MB
  bf16*  B1n    = (bf16*)alloc((size_t)5 * 640 * 640 * 2);       // 4.1 MB
  bf16*  B2n    = (bf16*)alloc((size_t)5 * 320 * 1280 * 2);      // 4.1 MB
  float* b1p    = (float*)alloc(5 * 640 * 4);
  float* b2p    = (float*)alloc(5 * 320 * 4);
  int*   rowptr = (int*)alloc((NN + 4) * 4);
  int*   packed = (int*)alloc(NE * 4);
  float* stats  = (float*)alloc(EMB2 * 4);
  float* coef   = (float*)alloc(EMB2 * 4);

  // Overlays into aggS (disjoint lifetimes):
  //  - CSR temporaries: used only before the first k_agg write.
  int*   cnt    = (int*)aggS;
  int*   cursor = cnt + NN;
  int*   bsum   = cursor + NN;
  int*   bpre   = bsum + 512;
  //  - pooled/t1/feats: used only after the last GEMM consumed aggS.
  float* pooled = (float*)aggS;
  float* t1     = pooled + (size_t)NG * EMB;
  float* feats  = t1 + (size_t)NG * EMB;

  // h1 split chunk buffer [CHUNK][1216] bf16 from remaining workspace.
  long long avail = (long long)ws_size - (long long)used - 1024;
  long long rows = avail / (1216 * 2);
  int CHUNK = (int)(rows < MPAD ? rows : MPAD);
  CHUNK &= ~127;
  if (CHUNK < 128) CHUNK = 128;
  bf16* h1S = (bf16*)(w + used);

  // CSR build (temporaries live in aggS region)
  hipMemsetAsync(cnt, 0, NN * 4, stream);
  k_count<<<(NE + 255) / 256, 256, 0, stream>>>(ei + NE, cnt);
  k_bsum<<<NB_SC, 256, 0, stream>>>(cnt, bsum);
  k_bscan<<<1, 512, 0, stream>>>(bsum, bpre);
  k_expand<<<NB_SC, 256, 0, stream>>>(cnt, bpre, rowptr, cursor);
  k_fill<<<(NE + 255) / 256, 256, 0, stream>>>(ei, ea, cursor, packed);

  // weights prep (split bf16, dup-free)
  k_prepw1<<<(5 * 640 * 640 + 255) / 256, 256, 0, stream>>>(W1, B1n);
  k_prepw2<<<(5 * 320 * 1280 + 255) / 256, 256, 0, stream>>>(W2, B2n);
  k_prepb<<<(5 * 640 + 5 * 320 + 255) / 256, 256, 0, stream>>>(b1, b2, b1p, b2p);

  // h0
  k_init<<<(NN * 75 + 255) / 256, 256, 0, stream>>>(
      x, (const float4*)atom_emb1, (const float4*)atom_emb2, (float4*)h);

  for (int l = 0; l < NLAYERS; ++l) {
    const float* be1 = bond_emb1 + (size_t)l * 6 * EMB;
    const float* be2 = bond_emb2 + (size_t)l * 3 * EMB;
    k_agg<<<NN / 4, 256, 0, stream>>>(h, rowptr, packed, be1, be2, aggS);

    for (int c0 = 0; c0 < NN; c0 += CHUNK) {
      int m = NN - c0 < CHUNK ? NN - c0 : CHUNK;
      int mt = (m + 127) / 128;
      // GEMM1: A=aggS (LDA 608, A_LO 304), B=B1n (LDB 640, B_LO 320), K_SECT=5
      k_mfma<5, 608, 640, 304, 320, 1><<<dim3(10, mt), 256, 0, stream>>>(
          aggS + (size_t)c0 * 608, B1n + (size_t)l * 640 * 640,
          b1p + l * 640, nullptr, h1S, 0);
      // GEMM2: A=h1S (LDA 1216, A_LO 608), B=B2n (LDB 1280, B_LO 640), K_SECT=10
      k_mfma<10, 1216, 1280, 608, 640, 2><<<dim3(5, mt), 256, 0, stream>>>(
          h1S, B2n + (size_t)l * 320 * 1280,
          b2p + l * 320, h + (size_t)c0 * 300, nullptr, NN - c0);
    }

    hipMemsetAsync(stats, 0, EMB2 * 4, stream);
    k_bnstats<<<512, 256, 0, stream>>>(h, stats);
    k_bnfinal<<<1, 320, 0, stream>>>(stats, bn_scale + (size_t)l * EMB,
                                     bn_bias + (size_t)l * EMB, coef);
    k_bnapply<<<(NN * 75 + 255) / 256, 256, 0, stream>>>((float4*)h, coef, l < NLAYERS - 1);
  }

  k_pool<<<NG, 256, 0, stream>>>(h, batch, pooled);
  k_rowgemm<true><<<NG, 256, 0, stream>>>(pooled, pW1, pb1, t1);
  k_rowgemm<false><<<NG, 256, 0, stream>>>(t1, pW2, pb2, feats);
  k_norm<<<NG, 256, 0, stream>>>(feats);
  k_logits<<<dim3(32, 32), dim3(16, 16), 0, stream>>>(feats, out);
}

// Round 5
// 7261.546 us; speedup vs baseline: 12.3640x; 2.1963x over previous
//
#include <hip/hip_runtime.h>

#define EMB   300
#define EMB2  600
#define NLAYERS 5
#define NN    100000
#define NE    400000
#define NG    1024
#define BN_EPS 1e-5f
#define MPAD  100096            // 782*128
#define NB_SC 391               // ceil(NN/256)
#define HLD   304               // h row stride (bf16): 300 real + 4 pad

// h   : [NN][304] bf16 (pad cols zero)
// aggS: [MPAD][608] bf16: col [0,304)=hi (300 real + 4 zero), [304,608)=lo
// h1S : [CHUNK][1216] bf16: col [0,608)=hi (600 real + 8 zero), [608,1216)=lo
// B1n : [L][640 n][640 k]  bf16: k [0,320)=W1h (kk<300 real), [320,640)=W1l
// B2n : [L][384 n][1280 k] bf16: k [0,640)=W2h (kk<600 real), [640,1280)=W2l
// Tile-tail overreads of A pair with ZERO B rows; garbage M-tail rows are
// masked by row_limit (GEMM2) or overwritten next chunk (h1S).

typedef __bf16 bf16;
typedef __attribute__((ext_vector_type(4))) __bf16 bf16x4;
typedef __attribute__((ext_vector_type(8))) __bf16 bf16x8;
typedef __attribute__((ext_vector_type(4))) float f32x4;

// ---------------- CSR build ----------------
__global__ void k_count(const int* __restrict__ dst, int* __restrict__ cnt) {
  int e = blockIdx.x * 256 + threadIdx.x;
  if (e < NE) atomicAdd(&cnt[dst[e]], 1);
}

__global__ void k_bsum(const int* __restrict__ cnt, int* __restrict__ bsum) {
  __shared__ int red[256];
  int i = blockIdx.x * 256 + threadIdx.x;
  red[threadIdx.x] = (i < NN) ? cnt[i] : 0;
  __syncthreads();
  for (int off = 128; off; off >>= 1) {
    if (threadIdx.x < off) red[threadIdx.x] += red[threadIdx.x + off];
    __syncthreads();
  }
  if (!threadIdx.x) bsum[blockIdx.x] = red[0];
}

__global__ void k_bscan(const int* __restrict__ bsum, int* __restrict__ bpre) {
  __shared__ int s[512];
  int t = threadIdx.x;
  s[t] = (t < NB_SC) ? bsum[t] : 0;
  __syncthreads();
  for (int off = 1; off < 512; off <<= 1) {
    int v = (t >= off) ? s[t - off] : 0;
    __syncthreads();
    s[t] += v;
    __syncthreads();
  }
  if (t < NB_SC) bpre[t] = t ? s[t - 1] : 0;
}

__global__ void k_expand(const int* __restrict__ cnt, const int* __restrict__ bpre,
                         int* __restrict__ rowptr, int* __restrict__ cursor) {
  __shared__ int s[256];
  int t = threadIdx.x, i = blockIdx.x * 256 + t;
  int v = (i < NN) ? cnt[i] : 0;
  s[t] = v;
  __syncthreads();
  for (int off = 1; off < 256; off <<= 1) {
    int u = (t >= off) ? s[t - off] : 0;
    __syncthreads();
    s[t] += u;
    __syncthreads();
  }
  int excl = bpre[blockIdx.x] + s[t] - v;
  if (i < NN) { rowptr[i] = excl; cursor[i] = excl; }
  if (i == NN - 1) rowptr[NN] = excl + v;
}

__global__ void k_fill(const int* __restrict__ ei, const int* __restrict__ ea,
                       int* __restrict__ cursor, int* __restrict__ packed) {
  int e = blockIdx.x * 256 + threadIdx.x;
  if (e >= NE) return;
  int d = ei[NE + e];
  int s = ei[e];
  int comb = ea[2 * e] * 3 + ea[2 * e + 1];
  int pos = atomicAdd(&cursor[d], 1);
  packed[pos] = s | (comb << 20);
}

// ---------------- init h (bf16) ----------------
__global__ void k_init(const int* __restrict__ x, const float4* __restrict__ ae1,
                       const float4* __restrict__ ae2, bf16* __restrict__ h) {
  int idx = blockIdx.x * 256 + threadIdx.x;
  if (idx >= NN * 76) return;
  int n = idx / 76, v = idx - n * 76;
  bf16x4 r4;
  if (v < 75) {
    int x0 = x[2 * n], x1 = x[2 * n + 1];
    float4 a = ae1[x0 * 75 + v], b = ae2[x1 * 75 + v];
    r4[0] = (bf16)(a.x + b.x); r4[1] = (bf16)(a.y + b.y);
    r4[2] = (bf16)(a.z + b.z); r4[3] = (bf16)(a.w + b.w);
  } else {
    r4[0] = r4[1] = r4[2] = r4[3] = (bf16)0.f;
  }
  *(bf16x4*)(h + (size_t)n * HLD + 4 * v) = r4;
}

// ---------------- weight/bias prep (split bf16, dup-free, N-major) ----------
__global__ void k_prepw1(const float* __restrict__ W1, bf16* __restrict__ B1n) {
  int idx = blockIdx.x * 256 + threadIdx.x;
  if (idx >= 5 * 640 * 640) return;
  int l = idx / (640 * 640), rem = idx - l * (640 * 640);
  int n = rem / 640, kp = rem - n * 640;
  int lo = kp >= 320;
  int kk = lo ? kp - 320 : kp;
  float w = (n < 600 && kk < 300) ? W1[(size_t)l * 300 * 600 + kk * 600 + n] : 0.f;
  bf16 hi = (bf16)w;
  B1n[idx] = lo ? (bf16)(w - (float)hi) : hi;
}

__global__ void k_prepw2(const float* __restrict__ W2, bf16* __restrict__ B2n) {
  int idx = blockIdx.x * 256 + threadIdx.x;
  if (idx >= 5 * 384 * 1280) return;
  int l = idx / (384 * 1280), rem = idx - l * (384 * 1280);
  int n = rem / 1280, kp = rem - n * 1280;
  int lo = kp >= 640;
  int kk = lo ? kp - 640 : kp;
  float w = (n < 300 && kk < 600) ? W2[(size_t)l * 600 * 300 + kk * 300 + n] : 0.f;
  bf16 hi = (bf16)w;
  B2n[idx] = lo ? (bf16)(w - (float)hi) : hi;
}

__global__ void k_prepb(const float* __restrict__ b1, const float* __restrict__ b2,
                        float* __restrict__ b1p, float* __restrict__ b2p) {
  int idx = blockIdx.x * 256 + threadIdx.x;
  if (idx < 5 * 640) {
    int l = idx / 640, n = idx - l * 640;
    b1p[idx] = (n < 600) ? b1[l * 600 + n] : 0.f;
  } else if (idx < 5 * 640 + 5 * 384) {
    int j = idx - 5 * 640;
    int l = j / 384, n = j - l * 384;
    b2p[j] = (n < 300) ? b2[l * 300 + n] : 0.f;
  }
}

// ---------------- aggregation (wave per node, bf16 h) -> split bf16 A ----------
__global__ __launch_bounds__(256) void k_agg(
    const bf16* __restrict__ h, const int* __restrict__ rowptr,
    const int* __restrict__ packed, const float* __restrict__ be1,
    const float* __restrict__ be2, bf16* __restrict__ aggS) {
  __shared__ float tab[9 * EMB];
  for (int i = threadIdx.x; i < 9 * EMB; i += 256) {
    int cc = i / EMB, d = i - cc * EMB;
    tab[i] = be1[(cc / 3) * EMB + d] + be2[(cc - (cc / 3) * 3) * EMB + d];
  }
  __syncthreads();
  int ty = threadIdx.x >> 6, lane = threadIdx.x & 63;
  int n = blockIdx.x * 4 + ty;
  float acc[5];
#pragma unroll
  for (int j = 0; j < 5; j++) {
    int d = lane + 64 * j;
    if (d < EMB) acc[j] = (float)h[(size_t)n * HLD + d] + be1[4 * EMB + d] + be2[d];
  }
  int e0 = rowptr[n], e1 = rowptr[n + 1];
  for (int e = e0; e < e1; ++e) {
    int pk = packed[e];
    const bf16* hr = &h[(size_t)(pk & 0xFFFFF) * HLD];
    const float* tr = &tab[(pk >> 20) * EMB];
#pragma unroll
    for (int j = 0; j < 5; j++) {
      int d = lane + 64 * j;
      if (d < EMB) acc[j] += (float)hr[d] + tr[d];
    }
  }
  bf16* row = aggS + (size_t)n * 608;
#pragma unroll
  for (int j = 0; j < 5; j++) {
    int d = lane + 64 * j;
    if (d < EMB) {
      float v = acc[j];
      bf16 hi = (bf16)v;
      row[d] = hi;
      row[304 + d] = (bf16)(v - (float)hi);
    } else if (d < 304) {
      row[d] = (bf16)0.f;
      row[304 + d] = (bf16)0.f;
    }
  }
}

// ---------------- MFMA GEMM (bf16x3 split, tripled K, dup-free B) ----------------
// Sections over kt: [0,KS)=Ah*Bh, [KS,2KS)=Al*Bh, [2KS,3KS)=Ah*Bl.
// Tile 128x128, BK=64, 4 waves (2x2, each 64x64 = 4x4 frags of 16x16),
// double-buffered XOR-swizzled LDS.
// MODE 1: C = h1S split (ld 1216): relu, hi at col (<608), lo at col+608.
// MODE 2: C = h bf16 (ld 304), write if col<304 && row<row_limit.
template <int K_SECT, int LDA, int LDB, int A_LO, int B_LO, int MODE>
__global__ __launch_bounds__(256) void k_mfma(
    const bf16* __restrict__ A,
    const bf16* __restrict__ Bn,
    const float* __restrict__ bias,
    bf16* __restrict__ C, int row_limit) {
  constexpr int KTILES = 3 * K_SECT;
  __shared__ __align__(16) bf16 As[2][128 * 64];
  __shared__ __align__(16) bf16 Bs[2][128 * 64];
  const int t = threadIdx.x, lane = t & 63, wid = t >> 6;
  const int wr = wid >> 1, wc = wid & 1;
  const int row0 = blockIdx.y * 128, n0 = blockIdx.x * 128;

  uint4 ra[4], rb[4];
  auto gload = [&](int kt) {
    int sect = (kt >= 2 * K_SECT) ? 2 : ((kt >= K_SECT) ? 1 : 0);
    int kbase = (kt - sect * K_SECT) * 64;
    int kA = kbase + (sect == 1 ? A_LO : 0);
    int kB = kbase + (sect == 2 ? B_LO : 0);
#pragma unroll
    for (int i = 0; i < 4; i++) {
      int idx = t + i * 256, r = idx >> 3, s = idx & 7;
      ra[i] = *(const uint4*)(A + (size_t)(row0 + r) * LDA + kA + s * 8);
      rb[i] = *(const uint4*)(Bn + (size_t)(n0 + r) * LDB + kB + s * 8);
    }
  };
  auto swr = [&](int buf) {
#pragma unroll
    for (int i = 0; i < 4; i++) {
      int idx = t + i * 256, r = idx >> 3, s = idx & 7;
      *(uint4*)((char*)&As[buf][0] + r * 128 + ((s ^ (r & 7)) << 4)) = ra[i];
      *(uint4*)((char*)&Bs[buf][0] + r * 128 + ((s ^ (r & 7)) << 4)) = rb[i];
    }
  };

  f32x4 acc[4][4] = {};
  gload(0);
  swr(0);
  int cur = 0;
#pragma unroll 2
  for (int kt = 0; kt < KTILES; kt++) {
    __syncthreads();
    if (kt + 1 < KTILES) gload(kt + 1);
#pragma unroll
    for (int kk = 0; kk < 2; kk++) {
      bf16x8 af[4], bfr[4];
#pragma unroll
      for (int mf = 0; mf < 4; mf++) {
        int r = wr * 64 + mf * 16 + (lane & 15);
        int c = (kk * 4 + (lane >> 4)) ^ (r & 7);
        af[mf] = *(const bf16x8*)((const char*)&As[cur][0] + r * 128 + (c << 4));
      }
#pragma unroll
      for (int nf = 0; nf < 4; nf++) {
        int n = wc * 64 + nf * 16 + (lane & 15);
        int c = (kk * 4 + (lane >> 4)) ^ (n & 7);
        bfr[nf] = *(const bf16x8*)((const char*)&Bs[cur][0] + n * 128 + (c << 4));
      }
#pragma unroll
      for (int mf = 0; mf < 4; mf++)
#pragma unroll
        for (int nf = 0; nf < 4; nf++)
          acc[mf][nf] = __builtin_amdgcn_mfma_f32_16x16x32_bf16(
              af[mf], bfr[nf], acc[mf][nf], 0, 0, 0);
    }
    if (kt + 1 < KTILES) swr(cur ^ 1);
    cur ^= 1;
  }

  const int rq = (lane >> 4) << 2;   // 0,4,8,12
  const int cl = lane & 15;
#pragma unroll
  for (int mf = 0; mf < 4; mf++)
#pragma unroll
    for (int nf = 0; nf < 4; nf++)
#pragma unroll
      for (int r = 0; r < 4; r++) {
        int grow = row0 + wr * 64 + mf * 16 + rq + r;
        int gcol = n0 + wc * 64 + nf * 16 + cl;
        float v = acc[mf][nf][r] + bias[gcol];
        if (MODE == 1) {
          if (gcol < 608) {
            v = fmaxf(v, 0.f);
            bf16 hi = (bf16)v;
            C[(size_t)grow * 1216 + gcol] = hi;
            C[(size_t)grow * 1216 + 608 + gcol] = (bf16)(v - (float)hi);
          }
        } else {
          if (grow < row_limit && gcol < HLD) C[(size_t)grow * HLD + gcol] = (bf16)v;
        }
      }
}

// ---------------- batchnorm (bf16 h) ----------------
__global__ void k_bnstats(const bf16* __restrict__ h, float* __restrict__ stats) {
  int b = blockIdx.x, t = threadIdx.x;
  int r0 = b * 196, r1 = r0 + 196; if (r1 > NN) r1 = NN;
  if (r0 >= NN) return;
  int c2 = t + 256;
  float s1 = 0, ss1 = 0, s2 = 0, ss2 = 0;
  for (int r = r0; r < r1; ++r) {
    float v1 = (float)h[(size_t)r * HLD + t];
    s1 += v1; ss1 += v1 * v1;
    if (c2 < EMB) { float v2 = (float)h[(size_t)r * HLD + c2]; s2 += v2; ss2 += v2 * v2; }
  }
  atomicAdd(&stats[t], s1); atomicAdd(&stats[EMB + t], ss1);
  if (c2 < EMB) { atomicAdd(&stats[c2], s2); atomicAdd(&stats[EMB + c2], ss2); }
}

// coef: a at [0,304), b at [304,608); pad cols -> 0
__global__ void k_bnfinal(const float* __restrict__ stats, const float* __restrict__ sc,
                          const float* __restrict__ bi, float* __restrict__ coef) {
  int c = threadIdx.x;
  if (c >= HLD) return;
  if (c < EMB) {
    float mean = stats[c] * (1.0f / NN);
    float var  = stats[EMB + c] * (1.0f / NN) - mean * mean;
    float inv  = rsqrtf(var + BN_EPS);
    float a = inv * sc[c];
    coef[c] = a;
    coef[HLD + c] = bi[c] - mean * a;
  } else {
    coef[c] = 0.f;
    coef[HLD + c] = 0.f;
  }
}

__global__ void k_bnapply(bf16* __restrict__ h, const float* __restrict__ coef, int relu) {
  int idx = blockIdx.x * 256 + threadIdx.x;
  if (idx >= NN * (HLD / 8)) return;
  int row = idx / (HLD / 8), v = idx - row * (HLD / 8);
  bf16x8 e = *(bf16x8*)(h + (size_t)row * HLD + 8 * v);
#pragma unroll
  for (int j = 0; j < 8; j++) {
    int c = 8 * v + j;
    float f = (float)e[j] * coef[c] + coef[HLD + c];
    if (relu) f = fmaxf(f, 0.f);
    e[j] = (bf16)f;
  }
  *(bf16x8*)(h + (size_t)row * HLD + 8 * v) = e;
}

// ---------------- pooling ----------------
__device__ __forceinline__ int lowerb(const int* a, int n, int v) {
  int lo = 0, hi = n;
  while (lo < hi) { int mid = (lo + hi) >> 1; if (a[mid] < v) lo = mid + 1; else hi = mid; }
  return lo;
}

__global__ void k_pool(const bf16* __restrict__ h, const int* __restrict__ batch,
                       float* __restrict__ pooled) {
  int g = blockIdx.x;
  __shared__ int se[2];
  if (threadIdx.x == 0) { se[0] = lowerb(batch, NN, g); se[1] = lowerb(batch, NN, g + 1); }
  __syncthreads();
  int start = se[0], end = se[1];
  float cntf = (float)((end - start) > 1 ? (end - start) : 1);
  for (int c = threadIdx.x; c < EMB; c += 256) {
    float s = 0.f;
    for (int r = start; r < end; ++r) s += (float)h[(size_t)r * HLD + c];
    pooled[(size_t)g * EMB + c] = s / cntf;
  }
}

// ---------------- projection head ----------------
template <bool RELU>
__global__ void k_rowgemm(const float* __restrict__ X, const float* __restrict__ W,
                          const float* __restrict__ bias, float* __restrict__ Y) {
  int g = blockIdx.x;
  __shared__ float row[EMB];
  for (int i = threadIdx.x; i < EMB; i += 256) row[i] = X[(size_t)g * EMB + i];
  __syncthreads();
  for (int c = threadIdx.x; c < EMB; c += 256) {
    float acc = bias[c];
    for (int k = 0; k < EMB; k++) acc += row[k] * W[(size_t)k * EMB + c];
    if (RELU) acc = fmaxf(acc, 0.f);
    Y[(size_t)g * EMB + c] = acc;
  }
}

__global__ void k_norm(float* __restrict__ p) {
  int g = blockIdx.x;
  __shared__ float red[256];
  float s = 0.f;
  for (int c = threadIdx.x; c < EMB; c += 256) { float v = p[(size_t)g * EMB + c]; s += v * v; }
  red[threadIdx.x] = s; __syncthreads();
  for (int off = 128; off > 0; off >>= 1) {
    if (threadIdx.x < off) red[threadIdx.x] += red[threadIdx.x + off];
    __syncthreads();
  }
  float inv = 1.0f / fmaxf(sqrtf(red[0]), 1e-12f);
  for (int c = threadIdx.x; c < EMB; c += 256) p[(size_t)g * EMB + c] *= inv;
}

__global__ __launch_bounds__(256) void k_logits(const float* __restrict__ feats,
                                                float* __restrict__ out) {
  __shared__ float SA[16 * EMB];
  __shared__ float SB[16 * EMB];
  int t = threadIdx.y * 16 + threadIdx.x;
  int i0 = blockIdx.y * 16, j0 = blockIdx.x * 16;
  for (int idx = t; idx < 16 * EMB; idx += 256) {
    int r = idx / EMB, c = idx - r * EMB;
    SA[idx] = feats[(size_t)(i0 + r) * EMB + c];
    SB[idx] = feats[(size_t)(512 + j0 + r) * EMB + c];
  }
  __syncthreads();
  float acc = 0.f;
  const float* a = &SA[threadIdx.y * EMB];
  const float* b = &SB[threadIdx.x * EMB];
  for (int k = 0; k < EMB; k++) acc += a[k] * b[k];
  out[(size_t)(i0 + threadIdx.y) * 512 + j0 + threadIdx.x] = acc / 0.04f;
}

// ---------------- host ----------------
extern "C" void kernel_launch(void* const* d_in, const int* in_sizes, int n_in,
                              void* d_out, int out_size, void* d_ws, size_t ws_size,
                              hipStream_t stream) {
  const int*   x         = (const int*)d_in[0];
  const int*   ei        = (const int*)d_in[1];
  const int*   ea        = (const int*)d_in[2];
  const int*   batch     = (const int*)d_in[3];
  const float* atom_emb1 = (const float*)d_in[4];
  const float* atom_emb2 = (const float*)d_in[5];
  const float* bond_emb1 = (const float*)d_in[6];
  const float* bond_emb2 = (const float*)d_in[7];
  const float* W1        = (const float*)d_in[8];
  const float* b1        = (const float*)d_in[9];
  const float* W2        = (const float*)d_in[10];
  const float* b2        = (const float*)d_in[11];
  const float* bn_scale  = (const float*)d_in[12];
  const float* bn_bias   = (const float*)d_in[13];
  const float* pW1       = (const float*)d_in[14];
  const float* pb1       = (const float*)d_in[15];
  const float* pW2       = (const float*)d_in[16];
  const float* pb2       = (const float*)d_in[17];
  float* out = (float*)d_out;

  char* w = (char*)d_ws;
  size_t used = 0;
  auto alloc = [&](size_t bytes) {
    char* p = w + used;
    used += (bytes + 255) & ~(size_t)255;
    return p;
  };
  bf16*  h      = (bf16*)alloc((size_t)NN * HLD * 2);            // 60.8 MB
  bf16*  aggS   = (bf16*)alloc((size_t)MPAD * 608 * 2);          // 121.7 MB
  bf16*  B1n    = (bf16*)alloc((size_t)5 * 640 * 640 * 2);       // 4.1 MB
  bf16*  B2n    = (bf16*)alloc((size_t)5 * 384 * 1280 * 2);      // 4.9 MB
  float* b1p    = (float*)alloc(5 * 640 * 4);
  float* b2p    = (float*)alloc(5 * 384 * 4);
  int*   rowptr = (int*)alloc((NN + 4) * 4);
  int*   packed = (int*)alloc(NE * 4);
  float* stats  = (float*)alloc(EMB2 * 4);
  float* coef   = (float*)alloc(2 * HLD * 4);

  // Overlays into aggS (disjoint lifetimes):
  int*   cnt    = (int*)aggS;           // CSR temps: dead before first k_agg
  int*   cursor = cnt + NN;
  int*   bsum   = cursor + NN;
  int*   bpre   = bsum + 512;
  float* pooled = (float*)aggS;         // head temps: after last GEMM1
  float* t1     = pooled + (size_t)NG * EMB;
  float* feats  = t1 + (size_t)NG * EMB;

  // h1 split chunk buffer [CHUNK][1216] bf16 from remaining workspace.
  long long avail = (long long)ws_size - (long long)used - 1024;
  long long rows = avail / (1216 * 2);
  int CHUNK = (int)(rows < MPAD ? rows : MPAD);
  CHUNK &= ~127;
  if (CHUNK < 128) CHUNK = 128;
  bf16* h1S = (bf16*)(w + used);

  // CSR build (temporaries live in aggS region)
  hipMemsetAsync(cnt, 0, NN * 4, stream);
  k_count<<<(NE + 255) / 256, 256, 0, stream>>>(ei + NE, cnt);
  k_bsum<<<NB_SC, 256, 0, stream>>>(cnt, bsum);
  k_bscan<<<1, 512, 0, stream>>>(bsum, bpre);
  k_expand<<<NB_SC, 256, 0, stream>>>(cnt, bpre, rowptr, cursor);
  k_fill<<<(NE + 255) / 256, 256, 0, stream>>>(ei, ea, cursor, packed);

  // zero aggS padding rows [NN, MPAD) once (tail A rows of last M-tile)
  hipMemsetAsync(aggS + (size_t)NN * 608, 0, (size_t)(MPAD - NN) * 608 * 2, stream);

  // weights prep (split bf16, dup-free)
  k_prepw1<<<(5 * 640 * 640 + 255) / 256, 256, 0, stream>>>(W1, B1n);
  k_prepw2<<<(5 * 384 * 1280 + 255) / 256, 256, 0, stream>>>(W2, B2n);
  k_prepb<<<(5 * 640 + 5 * 384 + 255) / 256, 256, 0, stream>>>(b1, b2, b1p, b2p);

  // h0 (bf16)
  k_init<<<(NN * 76 + 255) / 256, 256, 0, stream>>>(
      x, (const float4*)atom_emb1, (const float4*)atom_emb2, h);

  for (int l = 0; l < NLAYERS; ++l) {
    const float* be1 = bond_emb1 + (size_t)l * 6 * EMB;
    const float* be2 = bond_emb2 + (size_t)l * 3 * EMB;
    k_agg<<<NN / 4, 256, 0, stream>>>(h, rowptr, packed, be1, be2, aggS);

    for (int c0 = 0; c0 < NN; c0 += CHUNK) {
      int m = NN - c0 < CHUNK ? NN - c0 : CHUNK;
      int mt = (m + 127) / 128;
      // GEMM1: A=aggS (LDA 608, A_LO 304), B=B1n (LDB 640, B_LO 320), K_SECT=5
      k_mfma<5, 608, 640, 304, 320, 1><<<dim3(5, mt), 256, 0, stream>>>(
          aggS + (size_t)c0 * 608, B1n + (size_t)l * 640 * 640,
          b1p + l * 640, h1S, 0);
      // GEMM2: A=h1S (LDA 1216, A_LO 608), B=B2n (LDB 1280, B_LO 640), K_SECT=10
      k_mfma<10, 1216, 1280, 608, 640, 2><<<dim3(3, mt), 256, 0, stream>>>(
          h1S, B2n + (size_t)l * 384 * 1280,
          b2p + l * 384, h + (size_t)c0 * HLD, NN - c0);
    }

    hipMemsetAsync(stats, 0, EMB2 * 4, stream);
    k_bnstats<<<512, 256, 0, stream>>>(h, stats);
    k_bnfinal<<<1, 320, 0, stream>>>(stats, bn_scale + (size_t)l * EMB,
                                     bn_bias + (size_t)l * EMB, coef);
    k_bnapply<<<(NN * (HLD / 8) + 255) / 256, 256, 0, stream>>>(h, coef, l < NLAYERS - 1);
  }

  k_pool<<<NG, 256, 0, stream>>>(h, batch, pooled);
  k_rowgemm<true><<<NG, 256, 0, stream>>>(pooled, pW1, pb1, t1);
  k_rowgemm<false><<<NG, 256, 0, stream>>>(t1, pW2, pb2, feats);
  k_norm<<<NG, 256, 0, stream>>>(feats);
  k_logits<<<dim3(32, 32), dim3(16, 16), 0, stream>>>(feats, out);
}

// Round 6
// 5087.491 us; speedup vs baseline: 17.6475x; 1.4273x over previous
//
#include <hip/hip_runtime.h>

#define EMB   300
#define EMB2  600
#define NLAYERS 5
#define NN    100000
#define NE    400000
#define NG    1024
#define BN_EPS 1e-5f
#define MPAD  100096            // 782*128
#define NB_SC 391               // ceil(NN/256)
#define HLD   304               // h row stride (bf16): 300 real + 4 pad

// h   : [NN][304] bf16 (pad cols zero)
// aggS: [MPAD][608] bf16: col [0,304)=hi (300 real + 4 zero), [304,608)=lo
// h1S : [CHUNK][608] bf16 (hi only: 600 real + 8 zero)
// B1n : [L][640 n][640 k]  bf16: k [0,320)=W1h (kk<300 real), [320,640)=W1l
// B2n : [L][384 n][1280 k] bf16: k [0,640)=W2h (kk<600 real), [640,1280)=W2l
// A-tile overreads past the real K pair with ZERO B rows (kk>=real K zeroed),
// so no K bounds checks are needed anywhere.

typedef __bf16 bf16;
typedef __attribute__((ext_vector_type(4))) __bf16 bf16x4;
typedef __attribute__((ext_vector_type(8))) __bf16 bf16x8;
typedef __attribute__((ext_vector_type(4))) float f32x4;

// ---------------- CSR build ----------------
__global__ void k_count(const int* __restrict__ dst, int* __restrict__ cnt) {
  int e = blockIdx.x * 256 + threadIdx.x;
  if (e < NE) atomicAdd(&cnt[dst[e]], 1);
}

__global__ void k_bsum(const int* __restrict__ cnt, int* __restrict__ bsum) {
  __shared__ int red[256];
  int i = blockIdx.x * 256 + threadIdx.x;
  red[threadIdx.x] = (i < NN) ? cnt[i] : 0;
  __syncthreads();
  for (int off = 128; off; off >>= 1) {
    if (threadIdx.x < off) red[threadIdx.x] += red[threadIdx.x + off];
    __syncthreads();
  }
  if (!threadIdx.x) bsum[blockIdx.x] = red[0];
}

__global__ void k_bscan(const int* __restrict__ bsum, int* __restrict__ bpre) {
  __shared__ int s[512];
  int t = threadIdx.x;
  s[t] = (t < NB_SC) ? bsum[t] : 0;
  __syncthreads();
  for (int off = 1; off < 512; off <<= 1) {
    int v = (t >= off) ? s[t - off] : 0;
    __syncthreads();
    s[t] += v;
    __syncthreads();
  }
  if (t < NB_SC) bpre[t] = t ? s[t - 1] : 0;
}

__global__ void k_expand(const int* __restrict__ cnt, const int* __restrict__ bpre,
                         int* __restrict__ rowptr, int* __restrict__ cursor) {
  __shared__ int s[256];
  int t = threadIdx.x, i = blockIdx.x * 256 + t;
  int v = (i < NN) ? cnt[i] : 0;
  s[t] = v;
  __syncthreads();
  for (int off = 1; off < 256; off <<= 1) {
    int u = (t >= off) ? s[t - off] : 0;
    __syncthreads();
    s[t] += u;
    __syncthreads();
  }
  int excl = bpre[blockIdx.x] + s[t] - v;
  if (i < NN) { rowptr[i] = excl; cursor[i] = excl; }
  if (i == NN - 1) rowptr[NN] = excl + v;
}

__global__ void k_fill(const int* __restrict__ ei, const int* __restrict__ ea,
                       int* __restrict__ cursor, int* __restrict__ packed) {
  int e = blockIdx.x * 256 + threadIdx.x;
  if (e >= NE) return;
  int d = ei[NE + e];
  int s = ei[e];
  int comb = ea[2 * e] * 3 + ea[2 * e + 1];
  int pos = atomicAdd(&cursor[d], 1);
  packed[pos] = s | (comb << 20);
}

// ---------------- init h (bf16) ----------------
__global__ void k_init(const int* __restrict__ x, const float4* __restrict__ ae1,
                       const float4* __restrict__ ae2, bf16* __restrict__ h) {
  int idx = blockIdx.x * 256 + threadIdx.x;
  if (idx >= NN * 76) return;
  int n = idx / 76, v = idx - n * 76;
  bf16x4 r4;
  if (v < 75) {
    int x0 = x[2 * n], x1 = x[2 * n + 1];
    float4 a = ae1[x0 * 75 + v], b = ae2[x1 * 75 + v];
    r4[0] = (bf16)(a.x + b.x); r4[1] = (bf16)(a.y + b.y);
    r4[2] = (bf16)(a.z + b.z); r4[3] = (bf16)(a.w + b.w);
  } else {
    r4[0] = r4[1] = r4[2] = r4[3] = (bf16)0.f;
  }
  *(bf16x4*)(h + (size_t)n * HLD + 4 * v) = r4;
}

// ---------------- weight/bias prep (split bf16, dup-free, N-major) ----------
__global__ void k_prepw1(const float* __restrict__ W1, bf16* __restrict__ B1n) {
  int idx = blockIdx.x * 256 + threadIdx.x;
  if (idx >= 5 * 640 * 640) return;
  int l = idx / (640 * 640), rem = idx - l * (640 * 640);
  int n = rem / 640, kp = rem - n * 640;
  int lo = kp >= 320;
  int kk = lo ? kp - 320 : kp;
  float w = (n < 600 && kk < 300) ? W1[(size_t)l * 300 * 600 + kk * 600 + n] : 0.f;
  bf16 hi = (bf16)w;
  B1n[idx] = lo ? (bf16)(w - (float)hi) : hi;
}

__global__ void k_prepw2(const float* __restrict__ W2, bf16* __restrict__ B2n) {
  int idx = blockIdx.x * 256 + threadIdx.x;
  if (idx >= 5 * 384 * 1280) return;
  int l = idx / (384 * 1280), rem = idx - l * (384 * 1280);
  int n = rem / 1280, kp = rem - n * 1280;
  int lo = kp >= 640;
  int kk = lo ? kp - 640 : kp;
  float w = (n < 300 && kk < 600) ? W2[(size_t)l * 600 * 300 + kk * 300 + n] : 0.f;
  bf16 hi = (bf16)w;
  B2n[idx] = lo ? (bf16)(w - (float)hi) : hi;
}

__global__ void k_prepb(const float* __restrict__ b1, const float* __restrict__ b2,
                        float* __restrict__ b1p, float* __restrict__ b2p) {
  int idx = blockIdx.x * 256 + threadIdx.x;
  if (idx < 5 * 640) {
    int l = idx / 640, n = idx - l * 640;
    b1p[idx] = (n < 600) ? b1[l * 600 + n] : 0.f;
  } else if (idx < 5 * 640 + 5 * 384) {
    int j = idx - 5 * 640;
    int l = j / 384, n = j - l * 384;
    b2p[j] = (n < 300) ? b2[l * 300 + n] : 0.f;
  }
}

// ---------------- aggregation (wave per node, bf16 h) -> split bf16 A ----------
__global__ __launch_bounds__(256) void k_agg(
    const bf16* __restrict__ h, const int* __restrict__ rowptr,
    const int* __restrict__ packed, const float* __restrict__ be1,
    const float* __restrict__ be2, bf16* __restrict__ aggS) {
  __shared__ float tab[9 * EMB];
  for (int i = threadIdx.x; i < 9 * EMB; i += 256) {
    int cc = i / EMB, d = i - cc * EMB;
    tab[i] = be1[(cc / 3) * EMB + d] + be2[(cc - (cc / 3) * 3) * EMB + d];
  }
  __syncthreads();
  int ty = threadIdx.x >> 6, lane = threadIdx.x & 63;
  int n = blockIdx.x * 4 + ty;
  float acc[5];
#pragma unroll
  for (int j = 0; j < 5; j++) {
    int d = lane + 64 * j;
    if (d < EMB) acc[j] = (float)h[(size_t)n * HLD + d] + be1[4 * EMB + d] + be2[d];
  }
  int e0 = rowptr[n], e1 = rowptr[n + 1];
  for (int e = e0; e < e1; ++e) {
    int pk = packed[e];
    const bf16* hr = &h[(size_t)(pk & 0xFFFFF) * HLD];
    const float* tr = &tab[(pk >> 20) * EMB];
#pragma unroll
    for (int j = 0; j < 5; j++) {
      int d = lane + 64 * j;
      if (d < EMB) acc[j] += (float)hr[d] + tr[d];
    }
  }
  bf16* row = aggS + (size_t)n * 608;
#pragma unroll
  for (int j = 0; j < 5; j++) {
    int d = lane + 64 * j;
    if (d < EMB) {
      float v = acc[j];
      bf16 hi = (bf16)v;
      row[d] = hi;
      row[304 + d] = (bf16)(v - (float)hi);
    } else if (d < 304) {
      row[d] = (bf16)0.f;
      row[304 + d] = (bf16)0.f;
    }
  }
}

// ---------------- MFMA GEMM (split bf16, sectioned K, XCD-swizzled grid) -------
// NSECT=3: sections Ah*Bh, Al*Bh, Ah*Bl (A_LO = A lo-col offset, B_LO = B lo).
// NSECT=2: sections Ah*Bh, Ah*Bl (A hi only).
// Tile 128x128, BK=64, 4 waves (2x2), double-buffered XOR-swizzled LDS.
// 1-D grid NTILE*mt, bijective XCD remap (m204): all NTILE n-blocks of an
// M-panel are contiguous on ONE XCD -> A panel fetched from HBM once.
// MODE 1: C = h1S hi (ld 608): relu, write gcol<608.
// MODE 2: C = h bf16 (ld 304), write if gcol<304 && grow<row_limit.
template <int NSECT, int K_SECT, int LDA, int LDB, int A_LO, int B_LO, int MODE, int NTILE>
__global__ __launch_bounds__(256) void k_mfma(
    const bf16* __restrict__ A,
    const bf16* __restrict__ Bn,
    const float* __restrict__ bias,
    bf16* __restrict__ C, int row_limit) {
  constexpr int KTILES = NSECT * K_SECT;
  __shared__ __align__(16) bf16 As[2][128 * 64];
  __shared__ __align__(16) bf16 Bs[2][128 * 64];
  const int t = threadIdx.x, lane = t & 63, wid = t >> 6;
  const int wr = wid >> 1, wc = wid & 1;

  // bijective XCD swizzle
  const int nwg = (int)gridDim.x;
  const int q = nwg >> 3, r = nwg & 7;
  const int xcd = blockIdx.x & 7, slot = blockIdx.x >> 3;
  const int lin = (xcd < r ? xcd * (q + 1) : r * (q + 1) + (xcd - r) * q) + slot;
  const int row0 = (lin / NTILE) * 128, n0 = (lin % NTILE) * 128;

  uint4 ra[4], rb[4];
  auto gload = [&](int kt) {
    int sect = kt / K_SECT;
    int kbase = (kt - sect * K_SECT) * 64;
    int kA = kbase + ((NSECT == 3 && sect == 1) ? A_LO : 0);
    int kB = kbase + ((sect == NSECT - 1) ? B_LO : 0);
#pragma unroll
    for (int i = 0; i < 4; i++) {
      int idx = t + i * 256, rr = idx >> 3, s = idx & 7;
      ra[i] = *(const uint4*)(A + (size_t)(row0 + rr) * LDA + kA + s * 8);
      rb[i] = *(const uint4*)(Bn + (size_t)(n0 + rr) * LDB + kB + s * 8);
    }
  };
  auto swr = [&](int buf) {
#pragma unroll
    for (int i = 0; i < 4; i++) {
      int idx = t + i * 256, rr = idx >> 3, s = idx & 7;
      *(uint4*)((char*)&As[buf][0] + rr * 128 + ((s ^ (rr & 7)) << 4)) = ra[i];
      *(uint4*)((char*)&Bs[buf][0] + rr * 128 + ((s ^ (rr & 7)) << 4)) = rb[i];
    }
  };

  f32x4 acc[4][4] = {};
  gload(0);
  swr(0);
  int cur = 0;
#pragma unroll 2
  for (int kt = 0; kt < KTILES; kt++) {
    __syncthreads();
    if (kt + 1 < KTILES) gload(kt + 1);
#pragma unroll
    for (int kk = 0; kk < 2; kk++) {
      bf16x8 af[4], bfr[4];
#pragma unroll
      for (int mf = 0; mf < 4; mf++) {
        int rr = wr * 64 + mf * 16 + (lane & 15);
        int c = (kk * 4 + (lane >> 4)) ^ (rr & 7);
        af[mf] = *(const bf16x8*)((const char*)&As[cur][0] + rr * 128 + (c << 4));
      }
#pragma unroll
      for (int nf = 0; nf < 4; nf++) {
        int n = wc * 64 + nf * 16 + (lane & 15);
        int c = (kk * 4 + (lane >> 4)) ^ (n & 7);
        bfr[nf] = *(const bf16x8*)((const char*)&Bs[cur][0] + n * 128 + (c << 4));
      }
#pragma unroll
      for (int mf = 0; mf < 4; mf++)
#pragma unroll
        for (int nf = 0; nf < 4; nf++)
          acc[mf][nf] = __builtin_amdgcn_mfma_f32_16x16x32_bf16(
              af[mf], bfr[nf], acc[mf][nf], 0, 0, 0);
    }
    if (kt + 1 < KTILES) swr(cur ^ 1);
    cur ^= 1;
  }

  const int rq = (lane >> 4) << 2;   // 0,4,8,12
  const int cl = lane & 15;
#pragma unroll
  for (int mf = 0; mf < 4; mf++)
#pragma unroll
    for (int nf = 0; nf < 4; nf++)
#pragma unroll
      for (int rr = 0; rr < 4; rr++) {
        int grow = row0 + wr * 64 + mf * 16 + rq + rr;
        int gcol = n0 + wc * 64 + nf * 16 + cl;
        float v = acc[mf][nf][rr] + bias[gcol];
        if (MODE == 1) {
          if (gcol < 608) C[(size_t)grow * 608 + gcol] = (bf16)fmaxf(v, 0.f);
        } else {
          if (grow < row_limit && gcol < HLD) C[(size_t)grow * HLD + gcol] = (bf16)v;
        }
      }
}

// ---------------- batchnorm (bf16 h) ----------------
__global__ void k_bnstats(const bf16* __restrict__ h, float* __restrict__ stats) {
  int b = blockIdx.x, t = threadIdx.x;
  int r0 = b * 196, r1 = r0 + 196; if (r1 > NN) r1 = NN;
  if (r0 >= NN) return;
  int c2 = t + 256;
  float s1 = 0, ss1 = 0, s2 = 0, ss2 = 0;
  for (int r = r0; r < r1; ++r) {
    float v1 = (float)h[(size_t)r * HLD + t];
    s1 += v1; ss1 += v1 * v1;
    if (c2 < EMB) { float v2 = (float)h[(size_t)r * HLD + c2]; s2 += v2; ss2 += v2 * v2; }
  }
  atomicAdd(&stats[t], s1); atomicAdd(&stats[EMB + t], ss1);
  if (c2 < EMB) { atomicAdd(&stats[c2], s2); atomicAdd(&stats[EMB + c2], ss2); }
}

// coef: a at [0,304), b at [304,608); pad cols -> 0
__global__ void k_bnfinal(const float* __restrict__ stats, const float* __restrict__ sc,
                          const float* __restrict__ bi, float* __restrict__ coef) {
  int c = threadIdx.x;
  if (c >= HLD) return;
  if (c < EMB) {
    float mean = stats[c] * (1.0f / NN);
    float var  = stats[EMB + c] * (1.0f / NN) - mean * mean;
    float inv  = rsqrtf(var + BN_EPS);
    float a = inv * sc[c];
    coef[c] = a;
    coef[HLD + c] = bi[c] - mean * a;
  } else {
    coef[c] = 0.f;
    coef[HLD + c] = 0.f;
  }
}

__global__ void k_bnapply(bf16* __restrict__ h, const float* __restrict__ coef, int relu) {
  int idx = blockIdx.x * 256 + threadIdx.x;
  if (idx >= NN * (HLD / 8)) return;
  int row = idx / (HLD / 8), v = idx - row * (HLD / 8);
  bf16x8 e = *(bf16x8*)(h + (size_t)row * HLD + 8 * v);
#pragma unroll
  for (int j = 0; j < 8; j++) {
    int c = 8 * v + j;
    float f = (float)e[j] * coef[c] + coef[HLD + c];
    if (relu) f = fmaxf(f, 0.f);
    e[j] = (bf16)f;
  }
  *(bf16x8*)(h + (size_t)row * HLD + 8 * v) = e;
}

// ---------------- pooling ----------------
__device__ __forceinline__ int lowerb(const int* a, int n, int v) {
  int lo = 0, hi = n;
  while (lo < hi) { int mid = (lo + hi) >> 1; if (a[mid] < v) lo = mid + 1; else hi = mid; }
  return lo;
}

__global__ void k_pool(const bf16* __restrict__ h, const int* __restrict__ batch,
                       float* __restrict__ pooled) {
  int g = blockIdx.x;
  __shared__ int se[2];
  if (threadIdx.x == 0) { se[0] = lowerb(batch, NN, g); se[1] = lowerb(batch, NN, g + 1); }
  __syncthreads();
  int start = se[0], end = se[1];
  float cntf = (float)((end - start) > 1 ? (end - start) : 1);
  for (int c = threadIdx.x; c < EMB; c += 256) {
    float s = 0.f;
    for (int r = start; r < end; ++r) s += (float)h[(size_t)r * HLD + c];
    pooled[(size_t)g * EMB + c] = s / cntf;
  }
}

// ---------------- projection head ----------------
template <bool RELU>
__global__ void k_rowgemm(const float* __restrict__ X, const float* __restrict__ W,
                          const float* __restrict__ bias, float* __restrict__ Y) {
  int g = blockIdx.x;
  __shared__ float row[EMB];
  for (int i = threadIdx.x; i < EMB; i += 256) row[i] = X[(size_t)g * EMB + i];
  __syncthreads();
  for (int c = threadIdx.x; c < EMB; c += 256) {
    float acc = bias[c];
    for (int k = 0; k < EMB; k++) acc += row[k] * W[(size_t)k * EMB + c];
    if (RELU) acc = fmaxf(acc, 0.f);
    Y[(size_t)g * EMB + c] = acc;
  }
}

__global__ void k_norm(float* __restrict__ p) {
  int g = blockIdx.x;
  __shared__ float red[256];
  float s = 0.f;
  for (int c = threadIdx.x; c < EMB; c += 256) { float v = p[(size_t)g * EMB + c]; s += v * v; }
  red[threadIdx.x] = s; __syncthreads();
  for (int off = 128; off > 0; off >>= 1) {
    if (threadIdx.x < off) red[threadIdx.x] += red[threadIdx.x + off];
    __syncthreads();
  }
  float inv = 1.0f / fmaxf(sqrtf(red[0]), 1e-12f);
  for (int c = threadIdx.x; c < EMB; c += 256) p[(size_t)g * EMB + c] *= inv;
}

__global__ __launch_bounds__(256) void k_logits(const float* __restrict__ feats,
                                                float* __restrict__ out) {
  __shared__ float SA[16 * EMB];
  __shared__ float SB[16 * EMB];
  int t = threadIdx.y * 16 + threadIdx.x;
  int i0 = blockIdx.y * 16, j0 = blockIdx.x * 16;
  for (int idx = t; idx < 16 * EMB; idx += 256) {
    int r = idx / EMB, c = idx - r * EMB;
    SA[idx] = feats[(size_t)(i0 + r) * EMB + c];
    SB[idx] = feats[(size_t)(512 + j0 + r) * EMB + c];
  }
  __syncthreads();
  float acc = 0.f;
  const float* a = &SA[threadIdx.y * EMB];
  const float* b = &SB[threadIdx.x * EMB];
  for (int k = 0; k < EMB; k++) acc += a[k] * b[k];
  out[(size_t)(i0 + threadIdx.y) * 512 + j0 + threadIdx.x] = acc / 0.04f;
}

// ---------------- host ----------------
extern "C" void kernel_launch(void* const* d_in, const int* in_sizes, int n_in,
                              void* d_out, int out_size, void* d_ws, size_t ws_size,
                              hipStream_t stream) {
  const int*   x         = (const int*)d_in[0];
  const int*   ei        = (const int*)d_in[1];
  const int*   ea        = (const int*)d_in[2];
  const int*   batch     = (const int*)d_in[3];
  const float* atom_emb1 = (const float*)d_in[4];
  const float* atom_emb2 = (const float*)d_in[5];
  const float* bond_emb1 = (const float*)d_in[6];
  const float* bond_emb2 = (const float*)d_in[7];
  const float* W1        = (const float*)d_in[8];
  const float* b1        = (const float*)d_in[9];
  const float* W2        = (const float*)d_in[10];
  const float* b2        = (const float*)d_in[11];
  const float* bn_scale  = (const float*)d_in[12];
  const float* bn_bias   = (const float*)d_in[13];
  const float* pW1       = (const float*)d_in[14];
  const float* pb1       = (const float*)d_in[15];
  const float* pW2       = (const float*)d_in[16];
  const float* pb2       = (const float*)d_in[17];
  float* out = (float*)d_out;

  char* w = (char*)d_ws;
  size_t used = 0;
  auto alloc = [&](size_t bytes) {
    char* p = w + used;
    used += (bytes + 255) & ~(size_t)255;
    return p;
  };
  bf16*  h      = (bf16*)alloc((size_t)NN * HLD * 2);            // 60.8 MB
  bf16*  aggS   = (bf16*)alloc((size_t)MPAD * 608 * 2);          // 121.7 MB
  bf16*  B1n    = (bf16*)alloc((size_t)5 * 640 * 640 * 2);       // 4.1 MB
  bf16*  B2n    = (bf16*)alloc((size_t)5 * 384 * 1280 * 2);      // 4.9 MB
  float* b1p    = (float*)alloc(5 * 640 * 4);
  float* b2p    = (float*)alloc(5 * 384 * 4);
  int*   rowptr = (int*)alloc((NN + 4) * 4);
  int*   packed = (int*)alloc(NE * 4);
  float* stats  = (float*)alloc(EMB2 * 4);
  float* coef   = (float*)alloc(2 * HLD * 4);

  // Overlays into aggS (disjoint lifetimes):
  int*   cnt    = (int*)aggS;           // CSR temps: dead before first k_agg
  int*   cursor = cnt + NN;
  int*   bsum   = cursor + NN;
  int*   bpre   = bsum + 512;
  float* pooled = (float*)aggS;         // head temps: after last GEMM1
  float* t1     = pooled + (size_t)NG * EMB;
  float* feats  = t1 + (size_t)NG * EMB;

  // h1 hi-only chunk buffer [CHUNK][608] bf16 from remaining workspace,
  // balanced chunk count (8 KB slack for tile-tail overreads).
  long long avail = (long long)ws_size - (long long)used - 8192;
  long long rows = avail / (608 * 2);
  if (rows > MPAD) rows = MPAD;
  if (rows < 128) rows = 128;
  int nch = (int)((NN + rows - 1) / rows);
  int CHUNK = ((NN / nch) + 127 + (NN % nch ? 128 : 0)) & ~127;
  CHUNK = ((NN + nch - 1) / nch + 127) & ~127;
  bf16* h1S = (bf16*)(w + used);

  // CSR build (temporaries live in aggS region)
  hipMemsetAsync(cnt, 0, NN * 4, stream);
  k_count<<<(NE + 255) / 256, 256, 0, stream>>>(ei + NE, cnt);
  k_bsum<<<NB_SC, 256, 0, stream>>>(cnt, bsum);
  k_bscan<<<1, 512, 0, stream>>>(bsum, bpre);
  k_expand<<<NB_SC, 256, 0, stream>>>(cnt, bpre, rowptr, cursor);
  k_fill<<<(NE + 255) / 256, 256, 0, stream>>>(ei, ea, cursor, packed);

  // zero aggS padding rows [NN, MPAD) once (tail A rows of last M-tile)
  hipMemsetAsync(aggS + (size_t)NN * 608, 0, (size_t)(MPAD - NN) * 608 * 2, stream);

  // weights prep (split bf16, dup-free)
  k_prepw1<<<(5 * 640 * 640 + 255) / 256, 256, 0, stream>>>(W1, B1n);
  k_prepw2<<<(5 * 384 * 1280 + 255) / 256, 256, 0, stream>>>(W2, B2n);
  k_prepb<<<(5 * 640 + 5 * 384 + 255) / 256, 256, 0, stream>>>(b1, b2, b1p, b2p);

  // h0 (bf16)
  k_init<<<(NN * 76 + 255) / 256, 256, 0, stream>>>(
      x, (const float4*)atom_emb1, (const float4*)atom_emb2, h);

  for (int l = 0; l < NLAYERS; ++l) {
    const float* be1 = bond_emb1 + (size_t)l * 6 * EMB;
    const float* be2 = bond_emb2 + (size_t)l * 3 * EMB;
    k_agg<<<NN / 4, 256, 0, stream>>>(h, rowptr, packed, be1, be2, aggS);

    for (int c0 = 0; c0 < NN; c0 += CHUNK) {
      int m = NN - c0 < CHUNK ? NN - c0 : CHUNK;
      int mt = (m + 127) / 128;
      // GEMM1: A=aggS split (608, A_LO 304), B=B1n (640, B_LO 320), 3 sects x 5
      k_mfma<3, 5, 608, 640, 304, 320, 1, 5><<<5 * mt, 256, 0, stream>>>(
          aggS + (size_t)c0 * 608, B1n + (size_t)l * 640 * 640,
          b1p + l * 640, h1S, 0);
      // GEMM2: A=h1S hi (608), B=B2n (1280, B_LO 640), 2 sects x 10
      k_mfma<2, 10, 608, 1280, 0, 640, 2, 3><<<3 * mt, 256, 0, stream>>>(
          h1S, B2n + (size_t)l * 384 * 1280,
          b2p + l * 384, h + (size_t)c0 * HLD, NN - c0);
    }

    hipMemsetAsync(stats, 0, EMB2 * 4, stream);
    k_bnstats<<<512, 256, 0, stream>>>(h, stats);
    k_bnfinal<<<1, 320, 0, stream>>>(stats, bn_scale + (size_t)l * EMB,
                                     bn_bias + (size_t)l * EMB, coef);
    k_bnapply<<<(NN * (HLD / 8) + 255) / 256, 256, 0, stream>>>(h, coef, l < NLAYERS - 1);
  }

  k_pool<<<NG, 256, 0, stream>>>(h, batch, pooled);
  k_rowgemm<true><<<NG, 256, 0, stream>>>(pooled, pW1, pb1, t1);
  k_rowgemm<false><<<NG, 256, 0, stream>>>(t1, pW2, pb2, feats);
  k_norm<<<NG, 256, 0, stream>>>(feats);
  k_logits<<<dim3(32, 32), dim3(16, 16), 0, stream>>>(feats, out);
}

// Round 7
// 3806.100 us; speedup vs baseline: 23.5889x; 1.3367x over previous
//
#include <hip/hip_runtime.h>

#define EMB   300
#define EMB2  600
#define NLAYERS 5
#define NN    100000
#define NE    400000
#define NG    1024
#define BN_EPS 1e-5f
#define MPAD  100096            // 782*128
#define NB_SC 391               // ceil(NN/256)
#define HLD   304               // h row stride (bf16): 300 real + 4 pad

// h   : [NN][304] bf16, RAW (pre-BN) layer output; BN applied on read.
// aggS: [MPAD][320] bf16 hi-only (300 real + 20 zero cols)
// h1S : [CHUNK][608] bf16 (600 real + 8 zero)
// B1n : [L][640 n][640 k]  : k [0,320)=W1h (kk<300 real), [320,640)=W1l
// B2n : [L][384 n][1280 k] : k [0,640)=W2h (kk<600 real), [640,1280)=W2l
// All A K-windows are 64-aligned; A overreads pair with ZERO B rows.
// stats: sum at [0,384), sumsq at [384,768)  (cols >=300 only ever add 0)

typedef __bf16 bf16;
typedef __attribute__((ext_vector_type(4))) __bf16 bf16x4;
typedef __attribute__((ext_vector_type(8))) __bf16 bf16x8;
typedef __attribute__((ext_vector_type(4))) float f32x4;

// ---------------- CSR build ----------------
__global__ void k_count(const int* __restrict__ dst, int* __restrict__ cnt) {
  int e = blockIdx.x * 256 + threadIdx.x;
  if (e < NE) atomicAdd(&cnt[dst[e]], 1);
}

__global__ void k_bsum(const int* __restrict__ cnt, int* __restrict__ bsum) {
  __shared__ int red[256];
  int i = blockIdx.x * 256 + threadIdx.x;
  red[threadIdx.x] = (i < NN) ? cnt[i] : 0;
  __syncthreads();
  for (int off = 128; off; off >>= 1) {
    if (threadIdx.x < off) red[threadIdx.x] += red[threadIdx.x + off];
    __syncthreads();
  }
  if (!threadIdx.x) bsum[blockIdx.x] = red[0];
}

__global__ void k_bscan(const int* __restrict__ bsum, int* __restrict__ bpre) {
  __shared__ int s[512];
  int t = threadIdx.x;
  s[t] = (t < NB_SC) ? bsum[t] : 0;
  __syncthreads();
  for (int off = 1; off < 512; off <<= 1) {
    int v = (t >= off) ? s[t - off] : 0;
    __syncthreads();
    s[t] += v;
    __syncthreads();
  }
  if (t < NB_SC) bpre[t] = t ? s[t - 1] : 0;
}

__global__ void k_expand(const int* __restrict__ cnt, const int* __restrict__ bpre,
                         int* __restrict__ rowptr, int* __restrict__ cursor) {
  __shared__ int s[256];
  int t = threadIdx.x, i = blockIdx.x * 256 + t;
  int v = (i < NN) ? cnt[i] : 0;
  s[t] = v;
  __syncthreads();
  for (int off = 1; off < 256; off <<= 1) {
    int u = (t >= off) ? s[t - off] : 0;
    __syncthreads();
    s[t] += u;
    __syncthreads();
  }
  int excl = bpre[blockIdx.x] + s[t] - v;
  if (i < NN) { rowptr[i] = excl; cursor[i] = excl; }
  if (i == NN - 1) rowptr[NN] = excl + v;
}

__global__ void k_fill(const int* __restrict__ ei, const int* __restrict__ ea,
                       int* __restrict__ cursor, int* __restrict__ packed) {
  int e = blockIdx.x * 256 + threadIdx.x;
  if (e >= NE) return;
  int d = ei[NE + e];
  int s = ei[e];
  int comb = ea[2 * e] * 3 + ea[2 * e + 1];
  int pos = atomicAdd(&cursor[d], 1);
  packed[pos] = s | (comb << 20);
}

// ---------------- init h (bf16, raw) ----------------
__global__ void k_init(const int* __restrict__ x, const float4* __restrict__ ae1,
                       const float4* __restrict__ ae2, bf16* __restrict__ h) {
  int idx = blockIdx.x * 256 + threadIdx.x;
  if (idx >= NN * 76) return;
  int n = idx / 76, v = idx - n * 76;
  bf16x4 r4;
  if (v < 75) {
    int x0 = x[2 * n], x1 = x[2 * n + 1];
    float4 a = ae1[x0 * 75 + v], b = ae2[x1 * 75 + v];
    r4[0] = (bf16)(a.x + b.x); r4[1] = (bf16)(a.y + b.y);
    r4[2] = (bf16)(a.z + b.z); r4[3] = (bf16)(a.w + b.w);
  } else {
    r4[0] = r4[1] = r4[2] = r4[3] = (bf16)0.f;
  }
  *(bf16x4*)(h + (size_t)n * HLD + 4 * v) = r4;
}

// ---------------- weight/bias prep (split bf16, dup-free, N-major) ----------
__global__ void k_prepw1(const float* __restrict__ W1, bf16* __restrict__ B1n) {
  int idx = blockIdx.x * 256 + threadIdx.x;
  if (idx >= 5 * 640 * 640) return;
  int l = idx / (640 * 640), rem = idx - l * (640 * 640);
  int n = rem / 640, kp = rem - n * 640;
  int lo = kp >= 320;
  int kk = lo ? kp - 320 : kp;
  float w = (n < 600 && kk < 300) ? W1[(size_t)l * 300 * 600 + kk * 600 + n] : 0.f;
  bf16 hi = (bf16)w;
  B1n[idx] = lo ? (bf16)(w - (float)hi) : hi;
}

__global__ void k_prepw2(const float* __restrict__ W2, bf16* __restrict__ B2n) {
  int idx = blockIdx.x * 256 + threadIdx.x;
  if (idx >= 5 * 384 * 1280) return;
  int l = idx / (384 * 1280), rem = idx - l * (384 * 1280);
  int n = rem / 1280, kp = rem - n * 1280;
  int lo = kp >= 640;
  int kk = lo ? kp - 640 : kp;
  float w = (n < 300 && kk < 600) ? W2[(size_t)l * 600 * 300 + kk * 300 + n] : 0.f;
  bf16 hi = (bf16)w;
  B2n[idx] = lo ? (bf16)(w - (float)hi) : hi;
}

__global__ void k_prepb(const float* __restrict__ b1, const float* __restrict__ b2,
                        float* __restrict__ b1p, float* __restrict__ b2p) {
  int idx = blockIdx.x * 256 + threadIdx.x;
  if (idx < 5 * 640) {
    int l = idx / 640, n = idx - l * 640;
    b1p[idx] = (n < 600) ? b1[l * 600 + n] : 0.f;
  } else if (idx < 5 * 640 + 5 * 384) {
    int j = idx - 5 * 640;
    int l = j / 384, n = j - l * 384;
    b2p[j] = (n < 300) ? b2[l * 300 + n] : 0.f;
  }
}

// ---------------- aggregation (wave per node) -------------------------------
// APPLY=1: h is raw; apply per-col affine (coef) + relu on every read.
__global__ __launch_bounds__(256) void k_bnid(float* __restrict__ coef) {
  int c = threadIdx.x;
  if (c < HLD) { coef[c] = 1.f; coef[HLD + c] = 0.f; }
}

template <int APPLY>
__global__ __launch_bounds__(256) void k_agg(
    const bf16* __restrict__ h, const int* __restrict__ rowptr,
    const int* __restrict__ packed, const float* __restrict__ be1,
    const float* __restrict__ be2, const float* __restrict__ coef,
    bf16* __restrict__ aggS) {
  __shared__ float tab[9 * EMB];
  for (int i = threadIdx.x; i < 9 * EMB; i += 256) {
    int cc = i / EMB, d = i - cc * EMB;
    tab[i] = be1[(cc / 3) * EMB + d] + be2[(cc - (cc / 3) * 3) * EMB + d];
  }
  __syncthreads();
  int ty = threadIdx.x >> 6, lane = threadIdx.x & 63;
  int n = blockIdx.x * 4 + ty;
  float a_[5], b_[5];
#pragma unroll
  for (int j = 0; j < 5; j++) {
    int d = lane + 64 * j;
    a_[j] = (APPLY && d < EMB) ? coef[d] : 1.f;
    b_[j] = (APPLY && d < EMB) ? coef[HLD + d] : 0.f;
  }
  float acc[5];
#pragma unroll
  for (int j = 0; j < 5; j++) {
    int d = lane + 64 * j;
    if (d < EMB) {
      float hv = (float)h[(size_t)n * HLD + d];
      if (APPLY) hv = fmaxf(fmaf(a_[j], hv, b_[j]), 0.f);
      acc[j] = hv + be1[4 * EMB + d] + be2[d];
    }
  }
  int e0 = rowptr[n], e1 = rowptr[n + 1];
  for (int e = e0; e < e1; ++e) {
    int pk = packed[e];
    const bf16* hr = &h[(size_t)(pk & 0xFFFFF) * HLD];
    const float* tr = &tab[(pk >> 20) * EMB];
#pragma unroll
    for (int j = 0; j < 5; j++) {
      int d = lane + 64 * j;
      if (d < EMB) {
        float hv = (float)hr[d];
        if (APPLY) hv = fmaxf(fmaf(a_[j], hv, b_[j]), 0.f);
        acc[j] += hv + tr[d];
      }
    }
  }
  bf16* row = aggS + (size_t)n * 320;
#pragma unroll
  for (int j = 0; j < 5; j++) {
    int d = lane + 64 * j;
    row[d] = (d < EMB) ? (bf16)acc[j] : (bf16)0.f;
  }
}

// ---------------- MFMA GEMM (split bf16, sectioned K, XCD-swizzled grid) -------
// NSECT=2: sections Ah*Bh, Ah*Bl (B_LO = B lo-section col offset).
// Tile 128x128, BK=64, 4 waves (2x2), double-buffered XOR-swizzled LDS.
// MODE 1: C = h1S (ld 608): relu, write gcol<608.
// MODE 2: C = h raw bf16 (ld 304), write if gcol<304 && grow<row_limit;
//         epilogue also accumulates per-col sum/sumsq into stats (BN fusion).
template <int K_SECT, int LDA, int LDB, int B_LO, int MODE, int NTILE>
__global__ __launch_bounds__(256) void k_mfma(
    const bf16* __restrict__ A,
    const bf16* __restrict__ Bn,
    const float* __restrict__ bias,
    bf16* __restrict__ C, float* __restrict__ stats, int row_limit) {
  constexpr int KTILES = 2 * K_SECT;
  __shared__ __align__(16) bf16 As[2][128 * 64];
  __shared__ __align__(16) bf16 Bs[2][128 * 64];
  const int t = threadIdx.x, lane = t & 63, wid = t >> 6;
  const int wr = wid >> 1, wc = wid & 1;

  // bijective XCD swizzle (m204)
  const int nwg = (int)gridDim.x;
  const int q = nwg >> 3, r = nwg & 7;
  const int xcd = blockIdx.x & 7, slot = blockIdx.x >> 3;
  const int lin = (xcd < r ? xcd * (q + 1) : r * (q + 1) + (xcd - r) * q) + slot;
  const int row0 = (lin / NTILE) * 128, n0 = (lin % NTILE) * 128;

  uint4 ra[4], rb[4];
  auto gload = [&](int kt) {
    int sect = kt / K_SECT;
    int kbase = (kt - sect * K_SECT) * 64;
    int kB = kbase + (sect ? B_LO : 0);
#pragma unroll
    for (int i = 0; i < 4; i++) {
      int idx = t + i * 256, rr = idx >> 3, s = idx & 7;
      ra[i] = *(const uint4*)(A + (size_t)(row0 + rr) * LDA + kbase + s * 8);
      rb[i] = *(const uint4*)(Bn + (size_t)(n0 + rr) * LDB + kB + s * 8);
    }
  };
  auto swr = [&](int buf) {
#pragma unroll
    for (int i = 0; i < 4; i++) {
      int idx = t + i * 256, rr = idx >> 3, s = idx & 7;
      *(uint4*)((char*)&As[buf][0] + rr * 128 + ((s ^ (rr & 7)) << 4)) = ra[i];
      *(uint4*)((char*)&Bs[buf][0] + rr * 128 + ((s ^ (rr & 7)) << 4)) = rb[i];
    }
  };

  f32x4 acc[4][4] = {};
  gload(0);
  swr(0);
  int cur = 0;
#pragma unroll 2
  for (int kt = 0; kt < KTILES; kt++) {
    __syncthreads();
    if (kt + 1 < KTILES) gload(kt + 1);
#pragma unroll
    for (int kk = 0; kk < 2; kk++) {
      bf16x8 af[4], bfr[4];
#pragma unroll
      for (int mf = 0; mf < 4; mf++) {
        int rr = wr * 64 + mf * 16 + (lane & 15);
        int c = (kk * 4 + (lane >> 4)) ^ (rr & 7);
        af[mf] = *(const bf16x8*)((const char*)&As[cur][0] + rr * 128 + (c << 4));
      }
#pragma unroll
      for (int nf = 0; nf < 4; nf++) {
        int n = wc * 64 + nf * 16 + (lane & 15);
        int c = (kk * 4 + (lane >> 4)) ^ (n & 7);
        bfr[nf] = *(const bf16x8*)((const char*)&Bs[cur][0] + n * 128 + (c << 4));
      }
#pragma unroll
      for (int mf = 0; mf < 4; mf++)
#pragma unroll
        for (int nf = 0; nf < 4; nf++)
          acc[mf][nf] = __builtin_amdgcn_mfma_f32_16x16x32_bf16(
              af[mf], bfr[nf], acc[mf][nf], 0, 0, 0);
    }
    if (kt + 1 < KTILES) swr(cur ^ 1);
    cur ^= 1;
  }

  const int rq = (lane >> 4) << 2;   // 0,4,8,12
  const int cl = lane & 15;
#pragma unroll
  for (int nf = 0; nf < 4; nf++) {
    const int gcol = n0 + wc * 64 + nf * 16 + cl;
    float s = 0.f, qq = 0.f;
#pragma unroll
    for (int mf = 0; mf < 4; mf++)
#pragma unroll
      for (int rr = 0; rr < 4; rr++) {
        int grow = row0 + wr * 64 + mf * 16 + rq + rr;
        float v = acc[mf][nf][rr] + bias[gcol];
        if (MODE == 1) {
          if (gcol < 608) C[(size_t)grow * 608 + gcol] = (bf16)fmaxf(v, 0.f);
        } else {
          if (grow < row_limit) {
            if (gcol < HLD) C[(size_t)grow * HLD + gcol] = (bf16)v;
            s += v; qq += v * v;
          }
        }
      }
    if (MODE == 2) {
      s  += __shfl_down(s, 32);  s  += __shfl_down(s, 16);
      qq += __shfl_down(qq, 32); qq += __shfl_down(qq, 16);
      if (lane < 16 && gcol < EMB) {
        atomicAdd(&stats[gcol], s);
        atomicAdd(&stats[384 + gcol], qq);
      }
    }
  }
}

// ---------------- BN coef from fused stats ----------------
__global__ void k_bnfinal(const float* __restrict__ stats, const float* __restrict__ sc,
                          const float* __restrict__ bi, float* __restrict__ coef) {
  int c = threadIdx.x;
  if (c >= HLD) return;
  if (c < EMB) {
    float mean = stats[c] * (1.0f / NN);
    float var  = stats[384 + c] * (1.0f / NN) - mean * mean;
    float inv  = rsqrtf(var + BN_EPS);
    float a = inv * sc[c];
    coef[c] = a;
    coef[HLD + c] = bi[c] - mean * a;
  } else {
    coef[c] = 0.f;
    coef[HLD + c] = 0.f;
  }
}

// ---------------- pooling (applies final layer's BN, no relu) ----------------
__device__ __forceinline__ int lowerb(const int* a, int n, int v) {
  int lo = 0, hi = n;
  while (lo < hi) { int mid = (lo + hi) >> 1; if (a[mid] < v) lo = mid + 1; else hi = mid; }
  return lo;
}

__global__ void k_pool(const bf16* __restrict__ h, const int* __restrict__ batch,
                       const float* __restrict__ coef, float* __restrict__ pooled) {
  int g = blockIdx.x;
  __shared__ int se[2];
  if (threadIdx.x == 0) { se[0] = lowerb(batch, NN, g); se[1] = lowerb(batch, NN, g + 1); }
  __syncthreads();
  int start = se[0], end = se[1];
  for (int c = threadIdx.x; c < EMB; c += 256) {
    float s = 0.f;
    for (int r = start; r < end; ++r) s += (float)h[(size_t)r * HLD + c];
    float outv = 0.f;
    if (end > start) {
      float m = s / (float)(end - start);
      outv = fmaf(coef[c], m, coef[HLD + c]);
    }
    pooled[(size_t)g * EMB + c] = outv;
  }
}

// ---------------- projection head ----------------
template <bool RELU>
__global__ void k_rowgemm(const float* __restrict__ X, const float* __restrict__ W,
                          const float* __restrict__ bias, float* __restrict__ Y) {
  int g = blockIdx.x;
  __shared__ float row[EMB];
  for (int i = threadIdx.x; i < EMB; i += 256) row[i] = X[(size_t)g * EMB + i];
  __syncthreads();
  for (int c = threadIdx.x; c < EMB; c += 256) {
    float acc = bias[c];
    for (int k = 0; k < EMB; k++) acc += row[k] * W[(size_t)k * EMB + c];
    if (RELU) acc = fmaxf(acc, 0.f);
    Y[(size_t)g * EMB + c] = acc;
  }
}

__global__ void k_norm(float* __restrict__ p) {
  int g = blockIdx.x;
  __shared__ float red[256];
  float s = 0.f;
  for (int c = threadIdx.x; c < EMB; c += 256) { float v = p[(size_t)g * EMB + c]; s += v * v; }
  red[threadIdx.x] = s; __syncthreads();
  for (int off = 128; off > 0; off >>= 1) {
    if (threadIdx.x < off) red[threadIdx.x] += red[threadIdx.x + off];
    __syncthreads();
  }
  float inv = 1.0f / fmaxf(sqrtf(red[0]), 1e-12f);
  for (int c = threadIdx.x; c < EMB; c += 256) p[(size_t)g * EMB + c] *= inv;
}

__global__ __launch_bounds__(256) void k_logits(const float* __restrict__ feats,
                                                float* __restrict__ out) {
  __shared__ float SA[16 * EMB];
  __shared__ float SB[16 * EMB];
  int t = threadIdx.y * 16 + threadIdx.x;
  int i0 = blockIdx.y * 16, j0 = blockIdx.x * 16;
  for (int idx = t; idx < 16 * EMB; idx += 256) {
    int r = idx / EMB, c = idx - r * EMB;
    SA[idx] = feats[(size_t)(i0 + r) * EMB + c];
    SB[idx] = feats[(size_t)(512 + j0 + r) * EMB + c];
  }
  __syncthreads();
  float acc = 0.f;
  const float* a = &SA[threadIdx.y * EMB];
  const float* b = &SB[threadIdx.x * EMB];
  for (int k = 0; k < EMB; k++) acc += a[k] * b[k];
  out[(size_t)(i0 + threadIdx.y) * 512 + j0 + threadIdx.x] = acc / 0.04f;
}

// ---------------- host ----------------
extern "C" void kernel_launch(void* const* d_in, const int* in_sizes, int n_in,
                              void* d_out, int out_size, void* d_ws, size_t ws_size,
                              hipStream_t stream) {
  const int*   x         = (const int*)d_in[0];
  const int*   ei        = (const int*)d_in[1];
  const int*   ea        = (const int*)d_in[2];
  const int*   batch     = (const int*)d_in[3];
  const float* atom_emb1 = (const float*)d_in[4];
  const float* atom_emb2 = (const float*)d_in[5];
  const float* bond_emb1 = (const float*)d_in[6];
  const float* bond_emb2 = (const float*)d_in[7];
  const float* W1        = (const float*)d_in[8];
  const float* b1        = (const float*)d_in[9];
  const float* W2        = (const float*)d_in[10];
  const float* b2        = (const float*)d_in[11];
  const float* bn_scale  = (const float*)d_in[12];
  const float* bn_bias   = (const float*)d_in[13];
  const float* pW1       = (const float*)d_in[14];
  const float* pb1       = (const float*)d_in[15];
  const float* pW2       = (const float*)d_in[16];
  const float* pb2       = (const float*)d_in[17];
  float* out = (float*)d_out;

  char* w = (char*)d_ws;
  size_t used = 0;
  auto alloc = [&](size_t bytes) {
    char* p = w + used;
    used += (bytes + 255) & ~(size_t)255;
    return p;
  };
  bf16*  h      = (bf16*)alloc((size_t)NN * HLD * 2);            // 60.8 MB
  bf16*  aggS   = (bf16*)alloc((size_t)MPAD * 320 * 2);          // 64.1 MB
  bf16*  B1n    = (bf16*)alloc((size_t)5 * 640 * 640 * 2);       // 4.1 MB
  bf16*  B2n    = (bf16*)alloc((size_t)5 * 384 * 1280 * 2);      // 4.9 MB
  float* b1p    = (float*)alloc(5 * 640 * 4);
  float* b2p    = (float*)alloc(5 * 384 * 4);
  int*   rowptr = (int*)alloc((NN + 4) * 4);
  int*   packed = (int*)alloc(NE * 4);
  float* stats  = (float*)alloc(768 * 4);
  float* coef   = (float*)alloc(2 * HLD * 4);

  // Overlays into aggS (disjoint lifetimes):
  int*   cnt    = (int*)aggS;           // CSR temps: dead before first k_agg
  int*   cursor = cnt + NN;
  int*   bsum   = cursor + NN;
  int*   bpre   = bsum + 512;
  float* pooled = (float*)aggS;         // head temps: after last GEMM1
  float* t1     = pooled + (size_t)NG * EMB;
  float* feats  = t1 + (size_t)NG * EMB;

  // h1 chunk buffer [CHUNK][608] bf16 from remaining workspace (8KB slack
  // for tile-tail overreads), balanced chunk count.
  long long avail = (long long)ws_size - (long long)used - 8192;
  long long rows = avail / (608 * 2);
  if (rows > MPAD) rows = MPAD;
  if (rows < 128) rows = 128;
  int nch = (int)((NN + rows - 1) / rows);
  int CHUNK = ((NN + nch - 1) / nch + 127) & ~127;
  bf16* h1S = (bf16*)(w + used);

  // CSR build (temporaries live in aggS region)
  hipMemsetAsync(cnt, 0, NN * 4, stream);
  k_count<<<(NE + 255) / 256, 256, 0, stream>>>(ei + NE, cnt);
  k_bsum<<<NB_SC, 256, 0, stream>>>(cnt, bsum);
  k_bscan<<<1, 512, 0, stream>>>(bsum, bpre);
  k_expand<<<NB_SC, 256, 0, stream>>>(cnt, bpre, rowptr, cursor);
  k_fill<<<(NE + 255) / 256, 256, 0, stream>>>(ei, ea, cursor, packed);

  // zero aggS padding rows [NN, MPAD)
  hipMemsetAsync(aggS + (size_t)NN * 320, 0, (size_t)(MPAD - NN) * 320 * 2, stream);

  // weights prep
  k_prepw1<<<(5 * 640 * 640 + 255) / 256, 256, 0, stream>>>(W1, B1n);
  k_prepw2<<<(5 * 384 * 1280 + 255) / 256, 256, 0, stream>>>(W2, B2n);
  k_prepb<<<(5 * 640 + 5 * 384 + 255) / 256, 256, 0, stream>>>(b1, b2, b1p, b2p);

  // h0 (raw bf16)
  k_init<<<(NN * 76 + 255) / 256, 256, 0, stream>>>(
      x, (const float4*)atom_emb1, (const float4*)atom_emb2, h);

  for (int l = 0; l < NLAYERS; ++l) {
    const float* be1 = bond_emb1 + (size_t)l * 6 * EMB;
    const float* be2 = bond_emb2 + (size_t)l * 3 * EMB;
    if (l == 0)
      k_agg<0><<<NN / 4, 256, 0, stream>>>(h, rowptr, packed, be1, be2, coef, aggS);
    else
      k_agg<1><<<NN / 4, 256, 0, stream>>>(h, rowptr, packed, be1, be2, coef, aggS);

    hipMemsetAsync(stats, 0, 768 * 4, stream);
    for (int c0 = 0; c0 < NN; c0 += CHUNK) {
      int m = NN - c0 < CHUNK ? NN - c0 : CHUNK;
      int mt = (m + 127) / 128;
      // GEMM1: A=aggS hi (320), B=B1n (640, B_LO 320), 2 sects x 5
      k_mfma<5, 320, 640, 320, 1, 5><<<5 * mt, 256, 0, stream>>>(
          aggS + (size_t)c0 * 320, B1n + (size_t)l * 640 * 640,
          b1p + l * 640, h1S, nullptr, 0);
      // GEMM2: A=h1S (608), B=B2n (1280, B_LO 640), 2 sects x 10, fused BN stats
      k_mfma<10, 608, 1280, 640, 2, 3><<<3 * mt, 256, 0, stream>>>(
          h1S, B2n + (size_t)l * 384 * 1280,
          b2p + l * 384, h + (size_t)c0 * HLD, stats, NN - c0);
    }
    k_bnfinal<<<1, 320, 0, stream>>>(stats, bn_scale + (size_t)l * EMB,
                                     bn_bias + (size_t)l * EMB, coef);
  }

  k_pool<<<NG, 256, 0, stream>>>(h, batch, coef, pooled);
  k_rowgemm<true><<<NG, 256, 0, stream>>>(pooled, pW1, pb1, t1);
  k_rowgemm<false><<<NG, 256, 0, stream>>>(t1, pW2, pb2, feats);
  k_norm<<<NG, 256, 0, stream>>>(feats);
  k_logits<<<dim3(32, 32), dim3(16, 16), 0, stream>>>(feats, out);
}

// Round 8
// 2266.863 us; speedup vs baseline: 39.6061x; 1.6790x over previous
//
#include <hip/hip_runtime.h>

#define EMB   300
#define EMB2  600
#define NLAYERS 5
#define NN    100000
#define NE    400000
#define NG    1024
#define BN_EPS 1e-5f
#define MPAD  100096            // 782*128
#define NB_SC 391               // ceil(NN/256)
#define HLD   304               // h row stride (bf16): 300 real + 4 pad

// h   : [NN][304] bf16, RAW (pre-BN) layer output; BN applied on read.
// aggS: [MPAD][320] bf16 hi-only (300 real + 20 zero cols)
// h1S : [MPAD][608] bf16 (600 real + 8 zero)
// B1n : [L][640 n][640 k]  : k [0,320)=W1h (kk<300 real), [320,640)=W1l
// B2n : [L][384 n][1280 k] : k [0,640)=W2h (kk<600 real), [640,1280)=W2l
// All A K-windows are 64-aligned; A overreads pair with ZERO B rows.
// stats: sum at [0,384), sumsq at [384,768)

typedef __bf16 bf16;
typedef __attribute__((ext_vector_type(4))) __bf16 bf16x4;
typedef __attribute__((ext_vector_type(8))) __bf16 bf16x8;
typedef __attribute__((ext_vector_type(4))) float f32x4;

typedef __attribute__((address_space(3))) unsigned int lds_uint;
typedef __attribute__((address_space(1))) const unsigned int gbl_uint;

__device__ __forceinline__ void gld_lds16(const bf16* g, bf16* l) {
  // async 16B/lane HBM->LDS; LDS dest = wave-uniform base + lane*16
  __builtin_amdgcn_global_load_lds((gbl_uint*)g, (lds_uint*)l, 16, 0, 0);
}

// ---------------- CSR build ----------------
__global__ void k_count(const int* __restrict__ dst, int* __restrict__ cnt) {
  int e = blockIdx.x * 256 + threadIdx.x;
  if (e < NE) atomicAdd(&cnt[dst[e]], 1);
}

__global__ void k_bsum(const int* __restrict__ cnt, int* __restrict__ bsum) {
  __shared__ int red[256];
  int i = blockIdx.x * 256 + threadIdx.x;
  red[threadIdx.x] = (i < NN) ? cnt[i] : 0;
  __syncthreads();
  for (int off = 128; off; off >>= 1) {
    if (threadIdx.x < off) red[threadIdx.x] += red[threadIdx.x + off];
    __syncthreads();
  }
  if (!threadIdx.x) bsum[blockIdx.x] = red[0];
}

__global__ void k_bscan(const int* __restrict__ bsum, int* __restrict__ bpre) {
  __shared__ int s[512];
  int t = threadIdx.x;
  s[t] = (t < NB_SC) ? bsum[t] : 0;
  __syncthreads();
  for (int off = 1; off < 512; off <<= 1) {
    int v = (t >= off) ? s[t - off] : 0;
    __syncthreads();
    s[t] += v;
    __syncthreads();
  }
  if (t < NB_SC) bpre[t] = t ? s[t - 1] : 0;
}

__global__ void k_expand(const int* __restrict__ cnt, const int* __restrict__ bpre,
                         int* __restrict__ rowptr, int* __restrict__ cursor) {
  __shared__ int s[256];
  int t = threadIdx.x, i = blockIdx.x * 256 + t;
  int v = (i < NN) ? cnt[i] : 0;
  s[t] = v;
  __syncthreads();
  for (int off = 1; off < 256; off <<= 1) {
    int u = (t >= off) ? s[t - off] : 0;
    __syncthreads();
    s[t] += u;
    __syncthreads();
  }
  int excl = bpre[blockIdx.x] + s[t] - v;
  if (i < NN) { rowptr[i] = excl; cursor[i] = excl; }
  if (i == NN - 1) rowptr[NN] = excl + v;
}

__global__ void k_fill(const int* __restrict__ ei, const int* __restrict__ ea,
                       int* __restrict__ cursor, int* __restrict__ packed) {
  int e = blockIdx.x * 256 + threadIdx.x;
  if (e >= NE) return;
  int d = ei[NE + e];
  int s = ei[e];
  int comb = ea[2 * e] * 3 + ea[2 * e + 1];
  int pos = atomicAdd(&cursor[d], 1);
  packed[pos] = s | (comb << 20);
}

// ---------------- init h (bf16, raw) ----------------
__global__ void k_init(const int* __restrict__ x, const float4* __restrict__ ae1,
                       const float4* __restrict__ ae2, bf16* __restrict__ h) {
  int idx = blockIdx.x * 256 + threadIdx.x;
  if (idx >= NN * 76) return;
  int n = idx / 76, v = idx - n * 76;
  bf16x4 r4;
  if (v < 75) {
    int x0 = x[2 * n], x1 = x[2 * n + 1];
    float4 a = ae1[x0 * 75 + v], b = ae2[x1 * 75 + v];
    r4[0] = (bf16)(a.x + b.x); r4[1] = (bf16)(a.y + b.y);
    r4[2] = (bf16)(a.z + b.z); r4[3] = (bf16)(a.w + b.w);
  } else {
    r4[0] = r4[1] = r4[2] = r4[3] = (bf16)0.f;
  }
  *(bf16x4*)(h + (size_t)n * HLD + 4 * v) = r4;
}

// ---------------- weight/bias prep (split bf16, dup-free, N-major) ----------
__global__ void k_prepw1(const float* __restrict__ W1, bf16* __restrict__ B1n) {
  int idx = blockIdx.x * 256 + threadIdx.x;
  if (idx >= 5 * 640 * 640) return;
  int l = idx / (640 * 640), rem = idx - l * (640 * 640);
  int n = rem / 640, kp = rem - n * 640;
  int lo = kp >= 320;
  int kk = lo ? kp - 320 : kp;
  float w = (n < 600 && kk < 300) ? W1[(size_t)l * 300 * 600 + kk * 600 + n] : 0.f;
  bf16 hi = (bf16)w;
  B1n[idx] = lo ? (bf16)(w - (float)hi) : hi;
}

__global__ void k_prepw2(const float* __restrict__ W2, bf16* __restrict__ B2n) {
  int idx = blockIdx.x * 256 + threadIdx.x;
  if (idx >= 5 * 384 * 1280) return;
  int l = idx / (384 * 1280), rem = idx - l * (384 * 1280);
  int n = rem / 1280, kp = rem - n * 1280;
  int lo = kp >= 640;
  int kk = lo ? kp - 640 : kp;
  float w = (n < 300 && kk < 600) ? W2[(size_t)l * 600 * 300 + kk * 300 + n] : 0.f;
  bf16 hi = (bf16)w;
  B2n[idx] = lo ? (bf16)(w - (float)hi) : hi;
}

__global__ void k_prepb(const float* __restrict__ b1, const float* __restrict__ b2,
                        float* __restrict__ b1p, float* __restrict__ b2p) {
  int idx = blockIdx.x * 256 + threadIdx.x;
  if (idx < 5 * 640) {
    int l = idx / 640, n = idx - l * 640;
    b1p[idx] = (n < 600) ? b1[l * 600 + n] : 0.f;
  } else if (idx < 5 * 640 + 5 * 384) {
    int j = idx - 5 * 640;
    int l = j / 384, n = j - l * 384;
    b2p[j] = (n < 300) ? b2[l * 300 + n] : 0.f;
  }
}

// ---------------- aggregation (wave per node) -------------------------------
template <int APPLY>
__global__ __launch_bounds__(256) void k_agg(
    const bf16* __restrict__ h, const int* __restrict__ rowptr,
    const int* __restrict__ packed, const float* __restrict__ be1,
    const float* __restrict__ be2, const float* __restrict__ coef,
    bf16* __restrict__ aggS) {
  __shared__ float tab[9 * EMB];
  for (int i = threadIdx.x; i < 9 * EMB; i += 256) {
    int cc = i / EMB, d = i - cc * EMB;
    tab[i] = be1[(cc / 3) * EMB + d] + be2[(cc - (cc / 3) * 3) * EMB + d];
  }
  __syncthreads();
  int ty = threadIdx.x >> 6, lane = threadIdx.x & 63;
  int n = blockIdx.x * 4 + ty;
  float a_[5], b_[5];
#pragma unroll
  for (int j = 0; j < 5; j++) {
    int d = lane + 64 * j;
    a_[j] = (APPLY && d < EMB) ? coef[d] : 1.f;
    b_[j] = (APPLY && d < EMB) ? coef[HLD + d] : 0.f;
  }
  float acc[5];
#pragma unroll
  for (int j = 0; j < 5; j++) {
    int d = lane + 64 * j;
    if (d < EMB) {
      float hv = (float)h[(size_t)n * HLD + d];
      if (APPLY) hv = fmaxf(fmaf(a_[j], hv, b_[j]), 0.f);
      acc[j] = hv + be1[4 * EMB + d] + be2[d];
    }
  }
  int e0 = rowptr[n], e1 = rowptr[n + 1];
  for (int e = e0; e < e1; ++e) {
    int pk = packed[e];
    const bf16* hr = &h[(size_t)(pk & 0xFFFFF) * HLD];
    const float* tr = &tab[(pk >> 20) * EMB];
#pragma unroll
    for (int j = 0; j < 5; j++) {
      int d = lane + 64 * j;
      if (d < EMB) {
        float hv = (float)hr[d];
        if (APPLY) hv = fmaxf(fmaf(a_[j], hv, b_[j]), 0.f);
        acc[j] += hv + tr[d];
      }
    }
  }
  bf16* row = aggS + (size_t)n * 320;
#pragma unroll
  for (int j = 0; j < 5; j++) {
    int d = lane + 64 * j;
    row[d] = (d < EMB) ? (bf16)acc[j] : (bf16)0.f;
  }
}

// ---------------- MFMA GEMM (m97 structure: global_load_lds, 32 KB LDS) -------
// NSECT=2 sections: Ah*Bh, Ah*Bl (B_LO = B lo-section col offset).
// Tile 128x128, BK=64, 4 waves (2x2). Single-buffer LDS + 2 barriers/K-tile;
// XOR bank-swizzle achieved via PRE-SWIZZLED global source (linear LDS dest):
// lane l of an 8-row wave-instruction fetches global chunk (l&7)^(l>>3), so
// LDS slot (row, c) holds global chunk c^(row&7) — identical layout to the
// previous reg-staged swizzle; fragment reads unchanged (numerics identical).
// MODE 1: C = h1S (ld 608): relu, write gcol<608.
// MODE 2: C = h raw bf16 (ld 304), gcol<304 && grow<row_limit; fused BN stats.
template <int K_SECT, int LDA, int LDB, int B_LO, int MODE, int NTILE>
__global__ __launch_bounds__(256) void k_mfma(
    const bf16* __restrict__ A,
    const bf16* __restrict__ Bn,
    const float* __restrict__ bias,
    bf16* __restrict__ C, float* __restrict__ stats, int row_limit) {
  constexpr int KTILES = 2 * K_SECT;
  __shared__ __align__(16) bf16 As[128 * 64];
  __shared__ __align__(16) bf16 Bs[128 * 64];
  const int t = threadIdx.x, lane = t & 63, wid = t >> 6;
  const int wr = wid >> 1, wc = wid & 1;

  // bijective XCD swizzle (m204)
  const int nwg = (int)gridDim.x;
  const int q = nwg >> 3, r = nwg & 7;
  const int xcd = blockIdx.x & 7, slot = blockIdx.x >> 3;
  const int lin = (xcd < r ? xcd * (q + 1) : r * (q + 1) + (xcd - r) * q) + slot;
  const int row0 = (lin / NTILE) * 128, n0 = (lin % NTILE) * 128;

  // per-lane pre-swizzled source chunk + row-within-instruction
  const int csw = (lane & 7) ^ (lane >> 3);       // global 8-elem chunk index
  const int r8  = lane >> 3;                       // row within 8-row inst

  auto stage = [&](int kt) {
    int sect = kt / K_SECT;
    int kbase = (kt - sect * K_SECT) * 64;
    int kB = kbase + (sect ? B_LO : 0);
    const bf16* ga = A  + (size_t)(row0 + wid * 32 + r8) * LDA + kbase + csw * 8;
    const bf16* gb = Bn + (size_t)(n0  + wid * 32 + r8) * LDB + kB    + csw * 8;
#pragma unroll
    for (int i = 0; i < 4; i++) {
      gld_lds16(ga + (size_t)(i * 8) * LDA, &As[(wid * 32 + i * 8) * 64]);
      gld_lds16(gb + (size_t)(i * 8) * LDB, &Bs[(wid * 32 + i * 8) * 64]);
    }
  };

  f32x4 acc[4][4] = {};
#pragma unroll 2
  for (int kt = 0; kt < KTILES; kt++) {
    stage(kt);
    __syncthreads();               // drains vmcnt: staged tile visible
#pragma unroll
    for (int kk = 0; kk < 2; kk++) {
      bf16x8 af[4], bfr[4];
#pragma unroll
      for (int mf = 0; mf < 4; mf++) {
        int rr = wr * 64 + mf * 16 + (lane & 15);
        int c = (kk * 4 + (lane >> 4)) ^ (rr & 7);
        af[mf] = *(const bf16x8*)((const char*)&As[0] + rr * 128 + (c << 4));
      }
#pragma unroll
      for (int nf = 0; nf < 4; nf++) {
        int n = wc * 64 + nf * 16 + (lane & 15);
        int c = (kk * 4 + (lane >> 4)) ^ (n & 7);
        bfr[nf] = *(const bf16x8*)((const char*)&Bs[0] + n * 128 + (c << 4));
      }
#pragma unroll
      for (int mf = 0; mf < 4; mf++)
#pragma unroll
        for (int nf = 0; nf < 4; nf++)
          acc[mf][nf] = __builtin_amdgcn_mfma_f32_16x16x32_bf16(
              af[mf], bfr[nf], acc[mf][nf], 0, 0, 0);
    }
    __syncthreads();               // all reads done before next stage overwrites
  }

  const int rq = (lane >> 4) << 2;   // 0,4,8,12
  const int cl = lane & 15;
#pragma unroll
  for (int nf = 0; nf < 4; nf++) {
    const int gcol = n0 + wc * 64 + nf * 16 + cl;
    float s = 0.f, qq = 0.f;
#pragma unroll
    for (int mf = 0; mf < 4; mf++)
#pragma unroll
      for (int rr = 0; rr < 4; rr++) {
        int grow = row0 + wr * 64 + mf * 16 + rq + rr;
        float v = acc[mf][nf][rr] + bias[gcol];
        if (MODE == 1) {
          if (gcol < 608) C[(size_t)grow * 608 + gcol] = (bf16)fmaxf(v, 0.f);
        } else {
          if (grow < row_limit) {
            if (gcol < HLD) C[(size_t)grow * HLD + gcol] = (bf16)v;
            s += v; qq += v * v;
          }
        }
      }
    if (MODE == 2) {
      s  += __shfl_down(s, 32);  s  += __shfl_down(s, 16);
      qq += __shfl_down(qq, 32); qq += __shfl_down(qq, 16);
      if (lane < 16 && gcol < EMB) {
        atomicAdd(&stats[gcol], s);
        atomicAdd(&stats[384 + gcol], qq);
      }
    }
  }
}

// ---------------- BN coef from fused stats ----------------
__global__ void k_bnfinal(const float* __restrict__ stats, const float* __restrict__ sc,
                          const float* __restrict__ bi, float* __restrict__ coef) {
  int c = threadIdx.x;
  if (c >= HLD) return;
  if (c < EMB) {
    float mean = stats[c] * (1.0f / NN);
    float var  = stats[384 + c] * (1.0f / NN) - mean * mean;
    float inv  = rsqrtf(var + BN_EPS);
    float a = inv * sc[c];
    coef[c] = a;
    coef[HLD + c] = bi[c] - mean * a;
  } else {
    coef[c] = 0.f;
    coef[HLD + c] = 0.f;
  }
}

// ---------------- pooling (applies final layer's BN, no relu) ----------------
__device__ __forceinline__ int lowerb(const int* a, int n, int v) {
  int lo = 0, hi = n;
  while (lo < hi) { int mid = (lo + hi) >> 1; if (a[mid] < v) lo = mid + 1; else hi = mid; }
  return lo;
}

__global__ void k_pool(const bf16* __restrict__ h, const int* __restrict__ batch,
                       const float* __restrict__ coef, float* __restrict__ pooled) {
  int g = blockIdx.x;
  __shared__ int se[2];
  if (threadIdx.x == 0) { se[0] = lowerb(batch, NN, g); se[1] = lowerb(batch, NN, g + 1); }
  __syncthreads();
  int start = se[0], end = se[1];
  for (int c = threadIdx.x; c < EMB; c += 256) {
    float s = 0.f;
    for (int r = start; r < end; ++r) s += (float)h[(size_t)r * HLD + c];
    float outv = 0.f;
    if (end > start) {
      float m = s / (float)(end - start);
      outv = fmaf(coef[c], m, coef[HLD + c]);
    }
    pooled[(size_t)g * EMB + c] = outv;
  }
}

// ---------------- projection head ----------------
template <bool RELU>
__global__ void k_rowgemm(const float* __restrict__ X, const float* __restrict__ W,
                          const float* __restrict__ bias, float* __restrict__ Y) {
  int g = blockIdx.x;
  __shared__ float row[EMB];
  for (int i = threadIdx.x; i < EMB; i += 256) row[i] = X[(size_t)g * EMB + i];
  __syncthreads();
  for (int c = threadIdx.x; c < EMB; c += 256) {
    float acc = bias[c];
    for (int k = 0; k < EMB; k++) acc += row[k] * W[(size_t)k * EMB + c];
    if (RELU) acc = fmaxf(acc, 0.f);
    Y[(size_t)g * EMB + c] = acc;
  }
}

__global__ void k_norm(float* __restrict__ p) {
  int g = blockIdx.x;
  __shared__ float red[256];
  float s = 0.f;
  for (int c = threadIdx.x; c < EMB; c += 256) { float v = p[(size_t)g * EMB + c]; s += v * v; }
  red[threadIdx.x] = s; __syncthreads();
  for (int off = 128; off > 0; off >>= 1) {
    if (threadIdx.x < off) red[threadIdx.x] += red[threadIdx.x + off];
    __syncthreads();
  }
  float inv = 1.0f / fmaxf(sqrtf(red[0]), 1e-12f);
  for (int c = threadIdx.x; c < EMB; c += 256) p[(size_t)g * EMB + c] *= inv;
}

__global__ __launch_bounds__(256) void k_logits(const float* __restrict__ feats,
                                                float* __restrict__ out) {
  __shared__ float SA[16 * EMB];
  __shared__ float SB[16 * EMB];
  int t = threadIdx.y * 16 + threadIdx.x;
  int i0 = blockIdx.y * 16, j0 = blockIdx.x * 16;
  for (int idx = t; idx < 16 * EMB; idx += 256) {
    int r = idx / EMB, c = idx - r * EMB;
    SA[idx] = feats[(size_t)(i0 + r) * EMB + c];
    SB[idx] = feats[(size_t)(512 + j0 + r) * EMB + c];
  }
  __syncthreads();
  float acc = 0.f;
  const float* a = &SA[threadIdx.y * EMB];
  const float* b = &SB[threadIdx.x * EMB];
  for (int k = 0; k < EMB; k++) acc += a[k] * b[k];
  out[(size_t)(i0 + threadIdx.y) * 512 + j0 + threadIdx.x] = acc / 0.04f;
}

// ---------------- host ----------------
extern "C" void kernel_launch(void* const* d_in, const int* in_sizes, int n_in,
                              void* d_out, int out_size, void* d_ws, size_t ws_size,
                              hipStream_t stream) {
  const int*   x         = (const int*)d_in[0];
  const int*   ei        = (const int*)d_in[1];
  const int*   ea        = (const int*)d_in[2];
  const int*   batch     = (const int*)d_in[3];
  const float* atom_emb1 = (const float*)d_in[4];
  const float* atom_emb2 = (const float*)d_in[5];
  const float* bond_emb1 = (const float*)d_in[6];
  const float* bond_emb2 = (const float*)d_in[7];
  const float* W1        = (const float*)d_in[8];
  const float* b1        = (const float*)d_in[9];
  const float* W2        = (const float*)d_in[10];
  const float* b2        = (const float*)d_in[11];
  const float* bn_scale  = (const float*)d_in[12];
  const float* bn_bias   = (const float*)d_in[13];
  const float* pW1       = (const float*)d_in[14];
  const float* pb1       = (const float*)d_in[15];
  const float* pW2       = (const float*)d_in[16];
  const float* pb2       = (const float*)d_in[17];
  float* out = (float*)d_out;

  char* w = (char*)d_ws;
  size_t used = 0;
  auto alloc = [&](size_t bytes) {
    char* p = w + used;
    used += (bytes + 255) & ~(size_t)255;
    return p;
  };
  bf16*  h      = (bf16*)alloc((size_t)NN * HLD * 2);            // 60.8 MB
  bf16*  aggS   = (bf16*)alloc((size_t)MPAD * 320 * 2);          // 64.1 MB
  bf16*  B1n    = (bf16*)alloc((size_t)5 * 640 * 640 * 2);       // 4.1 MB
  bf16*  B2n    = (bf16*)alloc((size_t)5 * 384 * 1280 * 2);      // 4.9 MB
  float* b1p    = (float*)alloc(5 * 640 * 4);
  float* b2p    = (float*)alloc(5 * 384 * 4);
  int*   rowptr = (int*)alloc((NN + 4) * 4);
  int*   packed = (int*)alloc(NE * 4);
  float* stats  = (float*)alloc(768 * 4);
  float* coef   = (float*)alloc(2 * HLD * 4);

  // Overlays into aggS (disjoint lifetimes):
  int*   cnt    = (int*)aggS;           // CSR temps: dead before first k_agg
  int*   cursor = cnt + NN;
  int*   bsum   = cursor + NN;
  int*   bpre   = bsum + 512;
  float* pooled = (float*)aggS;         // head temps: after last GEMM1
  float* t1     = pooled + (size_t)NG * EMB;
  float* feats  = t1 + (size_t)NG * EMB;

  // h1 chunk buffer [CHUNK][608] bf16 from remaining workspace (8KB slack
  // for tile-tail overreads), balanced chunk count.
  long long avail = (long long)ws_size - (long long)used - 8192;
  long long rows = avail / (608 * 2);
  if (rows > MPAD) rows = MPAD;
  if (rows < 128) rows = 128;
  int nch = (int)((NN + rows - 1) / rows);
  int CHUNK = ((NN + nch - 1) / nch + 127) & ~127;
  bf16* h1S = (bf16*)(w + used);

  // CSR build (temporaries live in aggS region)
  hipMemsetAsync(cnt, 0, NN * 4, stream);
  k_count<<<(NE + 255) / 256, 256, 0, stream>>>(ei + NE, cnt);
  k_bsum<<<NB_SC, 256, 0, stream>>>(cnt, bsum);
  k_bscan<<<1, 512, 0, stream>>>(bsum, bpre);
  k_expand<<<NB_SC, 256, 0, stream>>>(cnt, bpre, rowptr, cursor);
  k_fill<<<(NE + 255) / 256, 256, 0, stream>>>(ei, ea, cursor, packed);

  // zero aggS padding rows [NN, MPAD)
  hipMemsetAsync(aggS + (size_t)NN * 320, 0, (size_t)(MPAD - NN) * 320 * 2, stream);

  // weights prep
  k_prepw1<<<(5 * 640 * 640 + 255) / 256, 256, 0, stream>>>(W1, B1n);
  k_prepw2<<<(5 * 384 * 1280 + 255) / 256, 256, 0, stream>>>(W2, B2n);
  k_prepb<<<(5 * 640 + 5 * 384 + 255) / 256, 256, 0, stream>>>(b1, b2, b1p, b2p);

  // h0 (raw bf16)
  k_init<<<(NN * 76 + 255) / 256, 256, 0, stream>>>(
      x, (const float4*)atom_emb1, (const float4*)atom_emb2, h);

  for (int l = 0; l < NLAYERS; ++l) {
    const float* be1 = bond_emb1 + (size_t)l * 6 * EMB;
    const float* be2 = bond_emb2 + (size_t)l * 3 * EMB;
    if (l == 0)
      k_agg<0><<<NN / 4, 256, 0, stream>>>(h, rowptr, packed, be1, be2, coef, aggS);
    else
      k_agg<1><<<NN / 4, 256, 0, stream>>>(h, rowptr, packed, be1, be2, coef, aggS);

    hipMemsetAsync(stats, 0, 768 * 4, stream);
    for (int c0 = 0; c0 < NN; c0 += CHUNK) {
      int m = NN - c0 < CHUNK ? NN - c0 : CHUNK;
      int mt = (m + 127) / 128;
      // GEMM1: A=aggS hi (320), B=B1n (640, B_LO 320), 2 sects x 5
      k_mfma<5, 320, 640, 320, 1, 5><<<5 * mt, 256, 0, stream>>>(
          aggS + (size_t)c0 * 320, B1n + (size_t)l * 640 * 640,
          b1p + l * 640, h1S, nullptr, 0);
      // GEMM2: A=h1S (608), B=B2n (1280, B_LO 640), 2 sects x 10, fused BN stats
      k_mfma<10, 608, 1280, 640, 2, 3><<<3 * mt, 256, 0, stream>>>(
          h1S, B2n + (size_t)l * 384 * 1280,
          b2p + l * 384, h + (size_t)c0 * HLD, stats, NN - c0);
    }
    k_bnfinal<<<1, 320, 0, stream>>>(stats, bn_scale + (size_t)l * EMB,
                                     bn_bias + (size_t)l * EMB, coef);
  }

  k_pool<<<NG, 256, 0, stream>>>(h, batch, coef, pooled);
  k_rowgemm<true><<<NG, 256, 0, stream>>>(pooled, pW1, pb1, t1);
  k_rowgemm<false><<<NG, 256, 0, stream>>>(t1, pW2, pb2, feats);
  k_norm<<<NG, 256, 0, stream>>>(feats);
  k_logits<<<dim3(32, 32), dim3(16, 16), 0, stream>>>(feats, out);
}

// Round 9
// 2010.107 us; speedup vs baseline: 44.6651x; 1.1277x over previous
//
#include <hip/hip_runtime.h>

#define EMB   300
#define EMB2  600
#define NLAYERS 5
#define NN    100000
#define NE    400000
#define NG    1024
#define BN_EPS 1e-5f
#define MPAD  100096            // 782*128
#define NB_SC 391               // ceil(NN/256)
#define HLD   304               // h row stride (bf16): 300 real + 4 pad

// h   : [NN][304] bf16, RAW (pre-BN) layer output; BN applied on read.
// aggS: [MPAD][320] bf16 hi-only (300 real + 20 zero cols)
// h1S : [MPAD][608] bf16 (600 real + 8 zero)
// B1n : [L][640 n][640 k]  : k [0,320)=W1h (kk<300 real), [320,640)=W1l
// B2n : [L][384 n][1280 k] : k [0,640)=W2h (kk<600 real), [640,1280)=W2l
// All A K-windows are 64-aligned; A overreads pair with ZERO B rows.
// stats: sum at [0,384), sumsq at [384,768)

typedef __bf16 bf16;
typedef __attribute__((ext_vector_type(4))) __bf16 bf16x4;
typedef __attribute__((ext_vector_type(8))) __bf16 bf16x8;
typedef __attribute__((ext_vector_type(4))) float f32x4;

typedef __attribute__((address_space(3))) unsigned int lds_uint;
typedef __attribute__((address_space(1))) const unsigned int gbl_uint;

__device__ __forceinline__ void gld_lds16(const bf16* g, bf16* l) {
  // async 16B/lane HBM->LDS; LDS dest = wave-uniform base + lane*16
  __builtin_amdgcn_global_load_lds((gbl_uint*)g, (lds_uint*)l, 16, 0, 0);
}

// ---------------- CSR build ----------------
__global__ void k_count(const int* __restrict__ dst, int* __restrict__ cnt) {
  int e = blockIdx.x * 256 + threadIdx.x;
  if (e < NE) atomicAdd(&cnt[dst[e]], 1);
}

__global__ void k_bsum(const int* __restrict__ cnt, int* __restrict__ bsum) {
  __shared__ int red[256];
  int i = blockIdx.x * 256 + threadIdx.x;
  red[threadIdx.x] = (i < NN) ? cnt[i] : 0;
  __syncthreads();
  for (int off = 128; off; off >>= 1) {
    if (threadIdx.x < off) red[threadIdx.x] += red[threadIdx.x + off];
    __syncthreads();
  }
  if (!threadIdx.x) bsum[blockIdx.x] = red[0];
}

__global__ void k_bscan(const int* __restrict__ bsum, int* __restrict__ bpre) {
  __shared__ int s[512];
  int t = threadIdx.x;
  s[t] = (t < NB_SC) ? bsum[t] : 0;
  __syncthreads();
  for (int off = 1; off < 512; off <<= 1) {
    int v = (t >= off) ? s[t - off] : 0;
    __syncthreads();
    s[t] += v;
    __syncthreads();
  }
  if (t < NB_SC) bpre[t] = t ? s[t - 1] : 0;
}

__global__ void k_expand(const int* __restrict__ cnt, const int* __restrict__ bpre,
                         int* __restrict__ rowptr, int* __restrict__ cursor) {
  __shared__ int s[256];
  int t = threadIdx.x, i = blockIdx.x * 256 + t;
  int v = (i < NN) ? cnt[i] : 0;
  s[t] = v;
  __syncthreads();
  for (int off = 1; off < 256; off <<= 1) {
    int u = (t >= off) ? s[t - off] : 0;
    __syncthreads();
    s[t] += u;
    __syncthreads();
  }
  int excl = bpre[blockIdx.x] + s[t] - v;
  if (i < NN) { rowptr[i] = excl; cursor[i] = excl; }
  if (i == NN - 1) rowptr[NN] = excl + v;
}

__global__ void k_fill(const int* __restrict__ ei, const int* __restrict__ ea,
                       int* __restrict__ cursor, int* __restrict__ packed) {
  int e = blockIdx.x * 256 + threadIdx.x;
  if (e >= NE) return;
  int d = ei[NE + e];
  int s = ei[e];
  int comb = ea[2 * e] * 3 + ea[2 * e + 1];
  int pos = atomicAdd(&cursor[d], 1);
  packed[pos] = s | (comb << 20);
}

// ---------------- init h (bf16, raw) ----------------
__global__ void k_init(const int* __restrict__ x, const float4* __restrict__ ae1,
                       const float4* __restrict__ ae2, bf16* __restrict__ h) {
  int idx = blockIdx.x * 256 + threadIdx.x;
  if (idx >= NN * 76) return;
  int n = idx / 76, v = idx - n * 76;
  bf16x4 r4;
  if (v < 75) {
    int x0 = x[2 * n], x1 = x[2 * n + 1];
    float4 a = ae1[x0 * 75 + v], b = ae2[x1 * 75 + v];
    r4[0] = (bf16)(a.x + b.x); r4[1] = (bf16)(a.y + b.y);
    r4[2] = (bf16)(a.z + b.z); r4[3] = (bf16)(a.w + b.w);
  } else {
    r4[0] = r4[1] = r4[2] = r4[3] = (bf16)0.f;
  }
  *(bf16x4*)(h + (size_t)n * HLD + 4 * v) = r4;
}

// ---------------- weight/bias prep (split bf16, dup-free, N-major) ----------
__global__ void k_prepw1(const float* __restrict__ W1, bf16* __restrict__ B1n) {
  int idx = blockIdx.x * 256 + threadIdx.x;
  if (idx >= 5 * 640 * 640) return;
  int l = idx / (640 * 640), rem = idx - l * (640 * 640);
  int n = rem / 640, kp = rem - n * 640;
  int lo = kp >= 320;
  int kk = lo ? kp - 320 : kp;
  float w = (n < 600 && kk < 300) ? W1[(size_t)l * 300 * 600 + kk * 600 + n] : 0.f;
  bf16 hi = (bf16)w;
  B1n[idx] = lo ? (bf16)(w - (float)hi) : hi;
}

__global__ void k_prepw2(const float* __restrict__ W2, bf16* __restrict__ B2n) {
  int idx = blockIdx.x * 256 + threadIdx.x;
  if (idx >= 5 * 384 * 1280) return;
  int l = idx / (384 * 1280), rem = idx - l * (384 * 1280);
  int n = rem / 1280, kp = rem - n * 1280;
  int lo = kp >= 640;
  int kk = lo ? kp - 640 : kp;
  float w = (n < 300 && kk < 600) ? W2[(size_t)l * 600 * 300 + kk * 300 + n] : 0.f;
  bf16 hi = (bf16)w;
  B2n[idx] = lo ? (bf16)(w - (float)hi) : hi;
}

__global__ void k_prepb(const float* __restrict__ b1, const float* __restrict__ b2,
                        float* __restrict__ b1p, float* __restrict__ b2p) {
  int idx = blockIdx.x * 256 + threadIdx.x;
  if (idx < 5 * 640) {
    int l = idx / 640, n = idx - l * 640;
    b1p[idx] = (n < 600) ? b1[l * 600 + n] : 0.f;
  } else if (idx < 5 * 640 + 5 * 384) {
    int j = idx - 5 * 640;
    int l = j / 384, n = j - l * 384;
    b2p[j] = (n < 300) ? b2[l * 300 + n] : 0.f;
  }
}

// ---------------- aggregation (wave per node) -------------------------------
template <int APPLY>
__global__ __launch_bounds__(256) void k_agg(
    const bf16* __restrict__ h, const int* __restrict__ rowptr,
    const int* __restrict__ packed, const float* __restrict__ be1,
    const float* __restrict__ be2, const float* __restrict__ coef,
    bf16* __restrict__ aggS) {
  __shared__ float tab[9 * EMB];
  for (int i = threadIdx.x; i < 9 * EMB; i += 256) {
    int cc = i / EMB, d = i - cc * EMB;
    tab[i] = be1[(cc / 3) * EMB + d] + be2[(cc - (cc / 3) * 3) * EMB + d];
  }
  __syncthreads();
  int ty = threadIdx.x >> 6, lane = threadIdx.x & 63;
  int n = blockIdx.x * 4 + ty;
  float a_[5], b_[5];
#pragma unroll
  for (int j = 0; j < 5; j++) {
    int d = lane + 64 * j;
    a_[j] = (APPLY && d < EMB) ? coef[d] : 1.f;
    b_[j] = (APPLY && d < EMB) ? coef[HLD + d] : 0.f;
  }
  float acc[5];
#pragma unroll
  for (int j = 0; j < 5; j++) {
    int d = lane + 64 * j;
    if (d < EMB) {
      float hv = (float)h[(size_t)n * HLD + d];
      if (APPLY) hv = fmaxf(fmaf(a_[j], hv, b_[j]), 0.f);
      acc[j] = hv + be1[4 * EMB + d] + be2[d];
    }
  }
  int e0 = rowptr[n], e1 = rowptr[n + 1];
  for (int e = e0; e < e1; ++e) {
    int pk = packed[e];
    const bf16* hr = &h[(size_t)(pk & 0xFFFFF) * HLD];
    const float* tr = &tab[(pk >> 20) * EMB];
#pragma unroll
    for (int j = 0; j < 5; j++) {
      int d = lane + 64 * j;
      if (d < EMB) {
        float hv = (float)hr[d];
        if (APPLY) hv = fmaxf(fmaf(a_[j], hv, b_[j]), 0.f);
        acc[j] += hv + tr[d];
      }
    }
  }
  bf16* row = aggS + (size_t)n * 320;
#pragma unroll
  for (int j = 0; j < 5; j++) {
    int d = lane + 64 * j;
    row[d] = (d < EMB) ? (bf16)acc[j] : (bf16)0.f;
  }
}

// ---------------- MFMA GEMM (A-stationary dual-section, global_load_lds) ------
// Per K-window (64 wide): stage As ONCE + both B sections (Bs0=Bh, Bs1=Bl),
// one barrier pair covers 64 MFMA/wave (2 sections x 2 kk x 4mf x 4nf).
// LDS 48 KB -> 3 blocks/CU (12 waves/CU, the m97 working point).
// XOR bank-swizzle via PRE-SWIZZLED global source chunk (l&7)^(l>>3), linear
// LDS dest; fragment reads use the matching XOR (numerics identical to r7/r8).
// MODE 1: C = h1S (ld 608): relu, write gcol<608.
// MODE 2: C = h raw bf16 (ld 304), gcol<304 && grow<row_limit; fused BN stats.
template <int K_SECT, int LDA, int LDB, int B_LO, int MODE, int NTILE>
__global__ __launch_bounds__(256) void k_mfma(
    const bf16* __restrict__ A,
    const bf16* __restrict__ Bn,
    const float* __restrict__ bias,
    bf16* __restrict__ C, float* __restrict__ stats, int row_limit) {
  __shared__ __align__(16) bf16 As[128 * 64];
  __shared__ __align__(16) bf16 Bs0[128 * 64];
  __shared__ __align__(16) bf16 Bs1[128 * 64];
  const int t = threadIdx.x, lane = t & 63, wid = t >> 6;
  const int wr = wid >> 1, wc = wid & 1;

  // bijective XCD swizzle (m204)
  const int nwg = (int)gridDim.x;
  const int q = nwg >> 3, r = nwg & 7;
  const int xcd = blockIdx.x & 7, slot = blockIdx.x >> 3;
  const int lin = (xcd < r ? xcd * (q + 1) : r * (q + 1) + (xcd - r) * q) + slot;
  const int row0 = (lin / NTILE) * 128, n0 = (lin % NTILE) * 128;

  // per-lane pre-swizzled source chunk + row-within-instruction
  const int csw = (lane & 7) ^ (lane >> 3);       // global 8-elem chunk index
  const int r8  = lane >> 3;                       // row within 8-row inst

  auto stage = [&](int kt) {
    int kbase = kt * 64;
    const bf16* ga = A  + (size_t)(row0 + wid * 32 + r8) * LDA + kbase + csw * 8;
    const bf16* gb = Bn + (size_t)(n0  + wid * 32 + r8) * LDB + kbase + csw * 8;
#pragma unroll
    for (int i = 0; i < 4; i++) {
      gld_lds16(ga + (size_t)(i * 8) * LDA,        &As [(wid * 32 + i * 8) * 64]);
      gld_lds16(gb + (size_t)(i * 8) * LDB,        &Bs0[(wid * 32 + i * 8) * 64]);
      gld_lds16(gb + (size_t)(i * 8) * LDB + B_LO, &Bs1[(wid * 32 + i * 8) * 64]);
    }
  };

  f32x4 acc[4][4] = {};
#pragma unroll 2
  for (int kt = 0; kt < K_SECT; kt++) {
    stage(kt);
    __syncthreads();               // drains vmcnt: staged tiles visible
#pragma unroll
    for (int kk = 0; kk < 2; kk++) {
      bf16x8 af[4], b0[4], b1[4];
#pragma unroll
      for (int mf = 0; mf < 4; mf++) {
        int rr = wr * 64 + mf * 16 + (lane & 15);
        int c = (kk * 4 + (lane >> 4)) ^ (rr & 7);
        af[mf] = *(const bf16x8*)((const char*)&As[0] + rr * 128 + (c << 4));
      }
#pragma unroll
      for (int nf = 0; nf < 4; nf++) {
        int n = wc * 64 + nf * 16 + (lane & 15);
        int c = (kk * 4 + (lane >> 4)) ^ (n & 7);
        b0[nf] = *(const bf16x8*)((const char*)&Bs0[0] + n * 128 + (c << 4));
        b1[nf] = *(const bf16x8*)((const char*)&Bs1[0] + n * 128 + (c << 4));
      }
#pragma unroll
      for (int mf = 0; mf < 4; mf++)
#pragma unroll
        for (int nf = 0; nf < 4; nf++) {
          acc[mf][nf] = __builtin_amdgcn_mfma_f32_16x16x32_bf16(
              af[mf], b0[nf], acc[mf][nf], 0, 0, 0);
          acc[mf][nf] = __builtin_amdgcn_mfma_f32_16x16x32_bf16(
              af[mf], b1[nf], acc[mf][nf], 0, 0, 0);
        }
    }
    __syncthreads();               // all reads done before next stage overwrites
  }

  const int rq = (lane >> 4) << 2;   // 0,4,8,12
  const int cl = lane & 15;
#pragma unroll
  for (int nf = 0; nf < 4; nf++) {
    const int gcol = n0 + wc * 64 + nf * 16 + cl;
    float s = 0.f, qq = 0.f;
#pragma unroll
    for (int mf = 0; mf < 4; mf++)
#pragma unroll
      for (int rr = 0; rr < 4; rr++) {
        int grow = row0 + wr * 64 + mf * 16 + rq + rr;
        float v = acc[mf][nf][rr] + bias[gcol];
        if (MODE == 1) {
          if (gcol < 608) C[(size_t)grow * 608 + gcol] = (bf16)fmaxf(v, 0.f);
        } else {
          if (grow < row_limit) {
            if (gcol < HLD) C[(size_t)grow * HLD + gcol] = (bf16)v;
            s += v; qq += v * v;
          }
        }
      }
    if (MODE == 2) {
      s  += __shfl_down(s, 32);  s  += __shfl_down(s, 16);
      qq += __shfl_down(qq, 32); qq += __shfl_down(qq, 16);
      if (lane < 16 && gcol < EMB) {
        atomicAdd(&stats[gcol], s);
        atomicAdd(&stats[384 + gcol], qq);
      }
    }
  }
}

// ---------------- BN coef from fused stats ----------------
__global__ void k_bnfinal(const float* __restrict__ stats, const float* __restrict__ sc,
                          const float* __restrict__ bi, float* __restrict__ coef) {
  int c = threadIdx.x;
  if (c >= HLD) return;
  if (c < EMB) {
    float mean = stats[c] * (1.0f / NN);
    float var  = stats[384 + c] * (1.0f / NN) - mean * mean;
    float inv  = rsqrtf(var + BN_EPS);
    float a = inv * sc[c];
    coef[c] = a;
    coef[HLD + c] = bi[c] - mean * a;
  } else {
    coef[c] = 0.f;
    coef[HLD + c] = 0.f;
  }
}

// ---------------- pooling (applies final layer's BN, no relu) ----------------
__device__ __forceinline__ int lowerb(const int* a, int n, int v) {
  int lo = 0, hi = n;
  while (lo < hi) { int mid = (lo + hi) >> 1; if (a[mid] < v) lo = mid + 1; else hi = mid; }
  return lo;
}

__global__ void k_pool(const bf16* __restrict__ h, const int* __restrict__ batch,
                       const float* __restrict__ coef, float* __restrict__ pooled) {
  int g = blockIdx.x;
  __shared__ int se[2];
  if (threadIdx.x == 0) { se[0] = lowerb(batch, NN, g); se[1] = lowerb(batch, NN, g + 1); }
  __syncthreads();
  int start = se[0], end = se[1];
  for (int c = threadIdx.x; c < EMB; c += 256) {
    float s = 0.f;
    for (int r = start; r < end; ++r) s += (float)h[(size_t)r * HLD + c];
    float outv = 0.f;
    if (end > start) {
      float m = s / (float)(end - start);
      outv = fmaf(coef[c], m, coef[HLD + c]);
    }
    pooled[(size_t)g * EMB + c] = outv;
  }
}

// ---------------- projection head ----------------
template <bool RELU>
__global__ void k_rowgemm(const float* __restrict__ X, const float* __restrict__ W,
                          const float* __restrict__ bias, float* __restrict__ Y) {
  int g = blockIdx.x;
  __shared__ float row[EMB];
  for (int i = threadIdx.x; i < EMB; i += 256) row[i] = X[(size_t)g * EMB + i];
  __syncthreads();
  for (int c = threadIdx.x; c < EMB; c += 256) {
    float acc = bias[c];
    for (int k = 0; k < EMB; k++) acc += row[k] * W[(size_t)k * EMB + c];
    if (RELU) acc = fmaxf(acc, 0.f);
    Y[(size_t)g * EMB + c] = acc;
  }
}

__global__ void k_norm(float* __restrict__ p) {
  int g = blockIdx.x;
  __shared__ float red[256];
  float s = 0.f;
  for (int c = threadIdx.x; c < EMB; c += 256) { float v = p[(size_t)g * EMB + c]; s += v * v; }
  red[threadIdx.x] = s; __syncthreads();
  for (int off = 128; off > 0; off >>= 1) {
    if (threadIdx.x < off) red[threadIdx.x] += red[threadIdx.x + off];
    __syncthreads();
  }
  float inv = 1.0f / fmaxf(sqrtf(red[0]), 1e-12f);
  for (int c = threadIdx.x; c < EMB; c += 256) p[(size_t)g * EMB + c] *= inv;
}

__global__ __launch_bounds__(256) void k_logits(const float* __restrict__ feats,
                                                float* __restrict__ out) {
  __shared__ float SA[16 * EMB];
  __shared__ float SB[16 * EMB];
  int t = threadIdx.y * 16 + threadIdx.x;
  int i0 = blockIdx.y * 16, j0 = blockIdx.x * 16;
  for (int idx = t; idx < 16 * EMB; idx += 256) {
    int r = idx / EMB, c = idx - r * EMB;
    SA[idx] = feats[(size_t)(i0 + r) * EMB + c];
    SB[idx] = feats[(size_t)(512 + j0 + r) * EMB + c];
  }
  __syncthreads();
  float acc = 0.f;
  const float* a = &SA[threadIdx.y * EMB];
  const float* b = &SB[threadIdx.x * EMB];
  for (int k = 0; k < EMB; k++) acc += a[k] * b[k];
  out[(size_t)(i0 + threadIdx.y) * 512 + j0 + threadIdx.x] = acc / 0.04f;
}

// ---------------- host ----------------
extern "C" void kernel_launch(void* const* d_in, const int* in_sizes, int n_in,
                              void* d_out, int out_size, void* d_ws, size_t ws_size,
                              hipStream_t stream) {
  const int*   x         = (const int*)d_in[0];
  const int*   ei        = (const int*)d_in[1];
  const int*   ea        = (const int*)d_in[2];
  const int*   batch     = (const int*)d_in[3];
  const float* atom_emb1 = (const float*)d_in[4];
  const float* atom_emb2 = (const float*)d_in[5];
  const float* bond_emb1 = (const float*)d_in[6];
  const float* bond_emb2 = (const float*)d_in[7];
  const float* W1        = (const float*)d_in[8];
  const float* b1        = (const float*)d_in[9];
  const float* W2        = (const float*)d_in[10];
  const float* b2        = (const float*)d_in[11];
  const float* bn_scale  = (const float*)d_in[12];
  const float* bn_bias   = (const float*)d_in[13];
  const float* pW1       = (const float*)d_in[14];
  const float* pb1       = (const float*)d_in[15];
  const float* pW2       = (const float*)d_in[16];
  const float* pb2       = (const float*)d_in[17];
  float* out = (float*)d_out;

  char* w = (char*)d_ws;
  size_t used = 0;
  auto alloc = [&](size_t bytes) {
    char* p = w + used;
    used += (bytes + 255) & ~(size_t)255;
    return p;
  };
  bf16*  h      = (bf16*)alloc((size_t)NN * HLD * 2);            // 60.8 MB
  bf16*  aggS   = (bf16*)alloc((size_t)MPAD * 320 * 2);          // 64.1 MB
  bf16*  B1n    = (bf16*)alloc((size_t)5 * 640 * 640 * 2);       // 4.1 MB
  bf16*  B2n    = (bf16*)alloc((size_t)5 * 384 * 1280 * 2);      // 4.9 MB
  float* b1p    = (float*)alloc(5 * 640 * 4);
  float* b2p    = (float*)alloc(5 * 384 * 4);
  int*   rowptr = (int*)alloc((NN + 4) * 4);
  int*   packed = (int*)alloc(NE * 4);
  float* stats  = (float*)alloc(768 * 4);
  float* coef   = (float*)alloc(2 * HLD * 4);

  // Overlays into aggS (disjoint lifetimes):
  int*   cnt    = (int*)aggS;           // CSR temps: dead before first k_agg
  int*   cursor = cnt + NN;
  int*   bsum   = cursor + NN;
  int*   bpre   = bsum + 512;
  float* pooled = (float*)aggS;         // head temps: after last GEMM1
  float* t1     = pooled + (size_t)NG * EMB;
  float* feats  = t1 + (size_t)NG * EMB;

  // h1 chunk buffer [CHUNK][608] bf16 from remaining workspace (8KB slack
  // for tile-tail overreads), balanced chunk count.
  long long avail = (long long)ws_size - (long long)used - 8192;
  long long rows = avail / (608 * 2);
  if (rows > MPAD) rows = MPAD;
  if (rows < 128) rows = 128;
  int nch = (int)((NN + rows - 1) / rows);
  int CHUNK = ((NN + nch - 1) / nch + 127) & ~127;
  bf16* h1S = (bf16*)(w + used);

  // CSR build (temporaries live in aggS region)
  hipMemsetAsync(cnt, 0, NN * 4, stream);
  k_count<<<(NE + 255) / 256, 256, 0, stream>>>(ei + NE, cnt);
  k_bsum<<<NB_SC, 256, 0, stream>>>(cnt, bsum);
  k_bscan<<<1, 512, 0, stream>>>(bsum, bpre);
  k_expand<<<NB_SC, 256, 0, stream>>>(cnt, bpre, rowptr, cursor);
  k_fill<<<(NE + 255) / 256, 256, 0, stream>>>(ei, ea, cursor, packed);

  // zero aggS padding rows [NN, MPAD)
  hipMemsetAsync(aggS + (size_t)NN * 320, 0, (size_t)(MPAD - NN) * 320 * 2, stream);

  // weights prep
  k_prepw1<<<(5 * 640 * 640 + 255) / 256, 256, 0, stream>>>(W1, B1n);
  k_prepw2<<<(5 * 384 * 1280 + 255) / 256, 256, 0, stream>>>(W2, B2n);
  k_prepb<<<(5 * 640 + 5 * 384 + 255) / 256, 256, 0, stream>>>(b1, b2, b1p, b2p);

  // h0 (raw bf16)
  k_init<<<(NN * 76 + 255) / 256, 256, 0, stream>>>(
      x, (const float4*)atom_emb1, (const float4*)atom_emb2, h);

  for (int l = 0; l < NLAYERS; ++l) {
    const float* be1 = bond_emb1 + (size_t)l * 6 * EMB;
    const float* be2 = bond_emb2 + (size_t)l * 3 * EMB;
    if (l == 0)
      k_agg<0><<<NN / 4, 256, 0, stream>>>(h, rowptr, packed, be1, be2, coef, aggS);
    else
      k_agg<1><<<NN / 4, 256, 0, stream>>>(h, rowptr, packed, be1, be2, coef, aggS);

    hipMemsetAsync(stats, 0, 768 * 4, stream);
    for (int c0 = 0; c0 < NN; c0 += CHUNK) {
      int m = NN - c0 < CHUNK ? NN - c0 : CHUNK;
      int mt = (m + 127) / 128;
      // GEMM1: A=aggS hi (320), B=B1n (640, B_LO 320), 5 K-windows x 2 sects
      k_mfma<5, 320, 640, 320, 1, 5><<<5 * mt, 256, 0, stream>>>(
          aggS + (size_t)c0 * 320, B1n + (size_t)l * 640 * 640,
          b1p + l * 640, h1S, nullptr, 0);
      // GEMM2: A=h1S (608), B=B2n (1280, B_LO 640), 10 K-windows x 2 sects
      k_mfma<10, 608, 1280, 640, 2, 3><<<3 * mt, 256, 0, stream>>>(
          h1S, B2n + (size_t)l * 384 * 1280,
          b2p + l * 384, h + (size_t)c0 * HLD, stats, NN - c0);
    }
    k_bnfinal<<<1, 320, 0, stream>>>(stats, bn_scale + (size_t)l * EMB,
                                     bn_bias + (size_t)l * EMB, coef);
  }

  k_pool<<<NG, 256, 0, stream>>>(h, batch, coef, pooled);
  k_rowgemm<true><<<NG, 256, 0, stream>>>(pooled, pW1, pb1, t1);
  k_rowgemm<false><<<NG, 256, 0, stream>>>(t1, pW2, pb2, feats);
  k_norm<<<NG, 256, 0, stream>>>(feats);
  k_logits<<<dim3(32, 32), dim3(16, 16), 0, stream>>>(feats, out);
}